// Round 10
// baseline (222.059 us; speedup 1.0000x reference)
//
#include <hip/hip_runtime.h>
#include <hip/hip_bf16.h>
#include <cstdint>

#define SCALE 0.17677669529663687f  // 32^-0.5

typedef float f4v __attribute__((ext_vector_type(4)));
typedef short s4v __attribute__((ext_vector_type(4)));
typedef short short8 __attribute__((ext_vector_type(8)));

__device__ __forceinline__ float b2f(short s){
  return __uint_as_float(((unsigned)(unsigned short)s) << 16);
}
__device__ __forceinline__ short f2b(float f){
  unsigned u = __float_as_uint(f);
  unsigned r = (u + 0x7fffu + ((u >> 16) & 1u)) >> 16;
  return (short)r;
}
__device__ __forceinline__ float geluf(float x){
  return 0.5f * x * (1.0f + erff(x * 0.7071067811865476f));
}
__device__ __forceinline__ f4v MFMA(short8 a, short8 b, f4v c){
  return __builtin_amdgcn_mfma_f32_16x16x32_bf16(a, b, c, 0, 0, 0);
}
// A/B-pattern fragment from row-major [*][ld]: row = rowBase+(l&15), k = kBase+8*(l>>4)
__device__ __forceinline__ short8 ldsA(const short* base, int ld, int rowBase, int kBase, int l){
  return *(const short8*)(base + (rowBase + (l & 15)) * ld + kBase + ((l >> 4) << 3));
}
// pack two C-layout f4v tiles into a bf16 operand fragment: slot k' = 4*tile + r
__device__ __forceinline__ short8 pack8(f4v a0, f4v a1, float scl){
  short8 o;
  #pragma unroll
  for (int k = 0; k < 4; ++k){
    o[k]     = f2b(a0[k] * scl);
    o[k + 4] = f2b(a1[k] * scl);
  }
  return o;
}
// token permutation for XTP storage: slot(n) matches P-pack positional pairing
__device__ __forceinline__ int permTok(int n){
  return (n & 32) | (((n >> 2) & 3) << 3) | (((n >> 4) & 1) << 2) | (n & 3);
}

// ws short-offsets
#define MTP_S   0         // 8 blks * 1024  (SA h0..3, EA h0..3; row-permuted M^T, SCALE folded)
#define FWP1_S  8192      // 48 blks * 4096 (fc11-blk * Wv, col-slot-permuted)
#define FWP2_S  204800    // 48 blks * 4096 (fc12)
#define FC2_S   401408    // 16384
#define M11_S   417792
#define M12_S   434176
#define M2_S    450560
#define POS_S   466944    // 2048
#define BIASP_B 937984    // bytes: 16384 f32, slot-permuted rel-pos bias
#define AW_B    1048576   // bytes: bf16 GEGLU-activation region [win][tok][128]

// ---------------------------------------------------------------- prep ----
__global__ void prep(const float* __restrict__ wea, const float* __restrict__ wsa,
                     const float* __restrict__ fc11, const float* __restrict__ fc12,
                     const float* __restrict__ fc2,  const float* __restrict__ m11,
                     const float* __restrict__ m12,  const float* __restrict__ m2,
                     const float* __restrict__ rpb,
                     short* __restrict__ wsS, float* __restrict__ biasP)
{
  int gid = blockIdx.x * 256 + threadIdx.x;
  int stride = gridDim.x * 256;
  // FWP1 / FWP2: blk = br*16 + h*4 + e (br: 0=SA, 1=EA1, 2=EA2); [o][s], s=8*h4+k',
  // c(s) = 16*(k'>>2) + 4*h4 + (k'&3);  FW[o][c] = sum_f fc[o][cb+f] * Wv_h[f][c]
  for (int id = gid; id < 786432; id += stride){
    int isB = (id >= 393216);
    int i2 = isB ? id - 393216 : id;
    const float* fc = isB ? fc12 : fc11;
    int blk = i2 >> 12, rem = i2 & 4095;
    int o = rem >> 5, s = rem & 31;
    int h4 = (s >> 3) & 3, kp = s & 7;
    int c = 16*(kp >> 2) + 4*h4 + (kp & 3);
    int br = blk >> 4, h = (blk >> 2) & 3, e = blk & 3;
    int cb = h*128 + e*32 + (br == 0 ? 0 : (br == 1 ? 512 : 1024));
    const float* w = (br == 0) ? wsa : wea;
    float acc = 0.f;
    for (int f = 0; f < 32; ++f)
      acc += fc[o*1536 + cb + f] * w[(256 + h*32 + f)*32 + c];
    wsS[(isB ? FWP2_S : FWP1_S) + blk*4096 + o*32 + s] = f2b(acc);
  }
  // MTP: u = br*4 + h (br 0=SA wsa, 1=EA wea); row jp holds M^T row b = 8*h4+4*t+r
  for (int id = gid; id < 8192; id += stride){
    int u = id >> 10, jp = (id >> 5) & 31, a = id & 31;
    int h = u & 3;
    const float* w = (u < 4) ? wsa : wea;
    int t = jp >> 4, h4 = (jp >> 2) & 3, r = jp & 3;
    int b = 8*h4 + 4*t + r;
    float acc = 0.f;
    for (int d = 0; d < 32; ++d)
      acc += w[(h*32 + d)*32 + a] * w[(128 + h*32 + d)*32 + b];
    wsS[MTP_S + u*1024 + jp*32 + a] = f2b(acc * SCALE);
  }
  // plain bf16 copies
  for (int id = gid; id < 65536; id += stride){
    const float* src; int base; int off = id & 16383;
    switch (id >> 14){
      case 0:  src = fc2; base = FC2_S; break;
      case 1:  src = m11; base = M11_S; break;
      case 2:  src = m12; base = M12_S; break;
      default: src = m2;  base = M2_S;  break;
    }
    wsS[base + off] = f2b(src[off]);
  }
  // biasP[hh][i][h4][tj*4+r] = bias[i][j = tj*16 + 4*h4 + r]
  for (int id = gid; id < 16384; id += stride){
    int hh = id >> 12, i = (id >> 6) & 63, h4 = (id >> 4) & 3, tj = (id >> 2) & 3, r = id & 3;
    int j = tj*16 + 4*h4 + r;
    int idx = ((i >> 3) - (j >> 3) + 7)*15 + ((i & 7) - (j & 7) + 7);
    biasP[id] = rpb[idx*4 + hh];
  }
  // sine positional table (bf16, [n][c])
  if (gid < 64){
    const float invT[8] = {1.f, 0.316227766f, 0.1f, 0.0316227766f,
                           0.01f, 0.00316227766f, 0.001f, 0.000316227766f};
    const float ANG = 6.28318530717958647692f / 8.000001f;
    float ay = (float)((gid >> 3) + 1) * ANG;
    float ax = (float)((gid & 7) + 1) * ANG;
    #pragma unroll
    for (int m = 0; m < 8; ++m){
      float s, cc;
      sincosf(ay * invT[m], &s, &cc);
      wsS[POS_S + gid*32 + 2*m]      = f2b(s);
      wsS[POS_S + gid*32 + 2*m + 1]  = f2b(cc);
      sincosf(ax * invT[m], &s, &cc);
      wsS[POS_S + gid*32 + 16 + 2*m] = f2b(s);
      wsS[POS_S + gid*32 + 17 + 2*m] = f2b(cc);
    }
  }
}

// -------------------------------------------------------------- kernel A --
// grid 1024 = 512 windows x 2 column-halves (beta). 256 thr = 4 waves; wave rho
// owns 16 query rows, all 4 heads, GEGLU cols [beta*64, beta*64+64).
// LDS: xw[4][64][32] + XTP[4][32][72] = 34816 B -> 4 blocks/CU (16 waves/CU)
// NOTE: no local arrays anywhere in the hot path (scratch-spill avoidance).
struct __align__(16) SmemA {
  short xw[8192];
  short xtp[9216];
};

__device__ __forceinline__ float smax16(f4v &s0, f4v &s1, f4v &s2, f4v &s3){
  float m = s0[0];
  #pragma unroll
  for (int r = 0; r < 4; ++r){
    m = fmaxf(m, s0[r]); m = fmaxf(m, s1[r]);
    m = fmaxf(m, s2[r]); m = fmaxf(m, s3[r]);
  }
  m = fmaxf(m, __shfl_xor(m, 16));
  m = fmaxf(m, __shfl_xor(m, 32));
  float sum = 0.f;
  #pragma unroll
  for (int r = 0; r < 4; ++r){
    float e0 = __expf(s0[r] - m), e1 = __expf(s1[r] - m);
    float e2 = __expf(s2[r] - m), e3 = __expf(s3[r] - m);
    s0[r] = e0; s1[r] = e1; s2[r] = e2; s3[r] = e3;
    sum += e0 + e1 + e2 + e3;
  }
  sum += __shfl_xor(sum, 16);
  sum += __shfl_xor(sum, 32);
  return __builtin_amdgcn_rcpf(sum);   // sum >= 1 -> safe approx reciprocal
}

__device__ __forceinline__ short8 projXq(const short* mtp, const short* xwE,
                                         int rho, int l){
  short8 xa = *(const short8*)(xwE + (rho*16 + (l & 15))*32 + ((l >> 4) << 3));
  f4v q0 = {0.f,0.f,0.f,0.f}, q1 = {0.f,0.f,0.f,0.f};
  q0 = MFMA(*(const short8*)(mtp + (l & 15)*32 + ((l >> 4) << 3)), xa, q0);
  q1 = MFMA(*(const short8*)(mtp + (16 + (l & 15))*32 + ((l >> 4) << 3)), xa, q1);
  return pack8(q0, q1, 1.f);
}

// g1/g2 (4 col-tiles = half width) += mfma(rp, FWP blk rows [beta*64 ..))
__device__ __forceinline__ void geglu8(short8 rp, const short* wsS, int blk, int beta,
                                       f4v* g1, f4v* g2, int l){
  const short* f1 = wsS + FWP1_S + blk*4096 + beta*2048 + (l & 15)*32 + ((l >> 4) << 3);
  #pragma unroll
  for (int ct = 0; ct < 4; ++ct)
    g1[ct] = MFMA(rp, *(const short8*)(f1 + ct*512), g1[ct]);
  const short* f2 = wsS + FWP2_S + blk*4096 + beta*2048 + (l & 15)*32 + ((l >> 4) << 3);
  #pragma unroll
  for (int ct = 0; ct < 4; ++ct)
    g2[ct] = MFMA(rp, *(const short8*)(f2 + ct*512), g2[ct]);
}

__device__ __forceinline__ void unitTail(f4v s0, f4v s1, f4v s2, f4v s3,
                                         const short* xtpE, const short* wsS,
                                         int blk, int blkFold, int beta,
                                         f4v* g1, f4v* g2, int l){
  float inv = smax16(s0, s1, s2, s3);
  short8 pk0 = pack8(s0, s1, 1.f);
  short8 pk1 = pack8(s2, s3, 1.f);
  f4v rt0 = {0.f,0.f,0.f,0.f}, rt1 = {0.f,0.f,0.f,0.f};
  const short* x0 = xtpE + (l & 15)*72 + ((l >> 4) << 3);
  const short* x1 = xtpE + (16 + (l & 15))*72 + ((l >> 4) << 3);
  rt0 = MFMA(*(const short8*)(x0), pk0, rt0);
  rt0 = MFMA(*(const short8*)(x0 + 32), pk1, rt0);
  rt1 = MFMA(*(const short8*)(x1), pk0, rt1);
  rt1 = MFMA(*(const short8*)(x1 + 32), pk1, rt1);
  short8 rp = pack8(rt0, rt1, inv);
  geglu8(rp, wsS, blk, beta, g1, g2, l);
  if (blkFold >= 0) geglu8(rp, wsS, blkFold, beta, g1, g2, l);
}

__global__ __launch_bounds__(256, 4) void kernelA(
    const float* __restrict__ x,
    const float* __restrict__ ln1g, const float* __restrict__ ln1b,
    const float* __restrict__ fc11b_, const float* __restrict__ fc12b_,
    const short* __restrict__ wsS, const float* __restrict__ biasP,
    short* __restrict__ aw)
{
  __shared__ SmemA sm;
  short* xw  = sm.xw;       // [e][n][c] = e*2048 + n*32 + c
  short* xtp = sm.xtp;      // [e][c][pos] = e*2304 + c*72 + pos

  const int t = threadIdx.x, l = t & 63, w = t >> 6;
  const int rho = w;
  // XCD-aware bijective swizzle (1024 % 8 == 0)
  const int bw = ((blockIdx.x & 7) << 7) | (blockIdx.x >> 3);
  const int win = bw >> 1, beta = bw & 1;
  const int b = win >> 8, hw = win & 255, hi = hw >> 4, wj = hw & 15;
  const int row0 = rho*16 + ((l >> 4) << 2);
  const short* posb = wsS + POS_S;

  // ---- phase 0: window load + LayerNorm, two-pass (no local arrays) ----
  {
    const int e = w, n = l;
    const int c = n >> 1, i0 = (n & 1) * 4;
    const float* src = x + ((size_t)((b*4 + e)*32 + c) * 128 + hi*8) * 128 + wj*8;
    float sum = 0.f, ssq = 0.f;
    #pragma unroll
    for (int ii = 0; ii < 4; ++ii){
      f4v a  = *(const f4v*)(src + (size_t)(i0 + ii)*128);
      f4v bb = *(const f4v*)(src + (size_t)(i0 + ii)*128 + 4);
      #pragma unroll
      for (int k = 0; k < 4; ++k){
        sum += a[k] + bb[k];
        ssq += a[k]*a[k] + bb[k]*bb[k];
      }
    }
    float mu = sum * (1.f/32.f);
    float rstd = rsqrtf(ssq * (1.f/32.f) - mu*mu + 1e-5f);
    int pn = permTok(n);
    #pragma unroll
    for (int ii = 0; ii < 4; ++ii){
      f4v a  = *(const f4v*)(src + (size_t)(i0 + ii)*128);
      f4v bb = *(const f4v*)(src + (size_t)(i0 + ii)*128 + 4);
      s4v o0, o1;
      #pragma unroll
      for (int k = 0; k < 4; ++k){
        int ch = ii*8 + k;
        o0[k] = f2b((a[k]  - mu)*rstd*ln1g[ch]     + ln1b[ch]);
        o1[k] = f2b((bb[k] - mu)*rstd*ln1g[ch + 4] + ln1b[ch + 4]);
      }
      *(s4v*)&xw[e*2048 + n*32 + ii*8]     = o0;
      *(s4v*)&xw[e*2048 + n*32 + ii*8 + 4] = o1;
      #pragma unroll
      for (int k = 0; k < 4; ++k){
        xtp[e*2304 + (ii*8 + k)*72 + pn]     = o0[k];
        xtp[e*2304 + (ii*8 + k + 4)*72 + pn] = o1[k];
      }
    }
  }
  __syncthreads();

  f4v g1[4], g2[4];
  #pragma unroll
  for (int i = 0; i < 4; ++i){
    g1[i] = (f4v){0.f,0.f,0.f,0.f};
    g2[i] = (f4v){0.f,0.f,0.f,0.f};
  }

  // ==== SA: all 4 heads; y cols [0,512) ====
  #pragma unroll 1
  for (int hh = 0; hh < 4; ++hh){
    const short* mtp = wsS + MTP_S + hh*1024;
    f4v s0 = {0.f,0.f,0.f,0.f}, s1 = {0.f,0.f,0.f,0.f};
    f4v s2 = {0.f,0.f,0.f,0.f}, s3 = {0.f,0.f,0.f,0.f};
    #pragma unroll
    for (int e = 0; e < 4; ++e){
      short8 xq = projXq(mtp, xw + e*2048, rho, l);
      s0 = MFMA(ldsA(xw + e*2048, 32,  0, 0, l), xq, s0);
      s1 = MFMA(ldsA(xw + e*2048, 32, 16, 0, l), xq, s1);
      s2 = MFMA(ldsA(xw + e*2048, 32, 32, 0, l), xq, s2);
      s3 = MFMA(ldsA(xw + e*2048, 32, 48, 0, l), xq, s3);
    }
    const float* bb = biasP + ((hh*64 + rho*16 + (l & 15))*4 + (l >> 4)) * 16;
    s0 += *(const f4v*)(bb);
    s1 += *(const f4v*)(bb + 4);
    s2 += *(const f4v*)(bb + 8);
    s3 += *(const f4v*)(bb + 12);
    float inv = smax16(s0, s1, s2, s3);
    short8 pk0 = pack8(s0, s1, 1.f);
    short8 pk1 = pack8(s2, s3, 1.f);
    #pragma unroll 1
    for (int dc = 0; dc < 4; ++dc){
      const short* xt = xtp + dc*2304;
      f4v rt0 = {0.f,0.f,0.f,0.f}, rt1 = {0.f,0.f,0.f,0.f};
      const short* x0 = xt + (l & 15)*72 + ((l >> 4) << 3);
      const short* x1 = xt + (16 + (l & 15))*72 + ((l >> 4) << 3);
      rt0 = MFMA(*(const short8*)(x0), pk0, rt0);
      rt0 = MFMA(*(const short8*)(x0 + 32), pk1, rt0);
      rt1 = MFMA(*(const short8*)(x1), pk0, rt1);
      rt1 = MFMA(*(const short8*)(x1 + 32), pk1, rt1);
      short8 rp = pack8(rt0, rt1, inv);
      geglu8(rp, wsS, hh*4 + dc, beta, g1, g2, l);
    }
  }

  // ---- xw/XTP -> +pos (in place)
  __syncthreads();
  {
    const int e = w, n = l;
    #pragma unroll
    for (int c4 = 0; c4 < 8; ++c4){
      s4v xa = *(const s4v*)&xw[e*2048 + n*32 + c4*4];
      s4v pa = *(const s4v*)(posb + n*32 + c4*4);
      s4v o;
      #pragma unroll
      for (int j = 0; j < 4; ++j) o[j] = f2b(b2f(xa[j]) + b2f(pa[j]));
      *(s4v*)&xw[e*2048 + n*32 + c4*4] = o;
    }
    int pn = permTok(n);
    #pragma unroll
    for (int c2 = 0; c2 < 32; ++c2){
      int idx = e*2304 + c2*72 + pn;
      xtp[idx] = f2b(b2f(xtp[idx]) + b2f(posb[n*32 + c2]));
    }
  }
  __syncthreads();

  // ==== EA: all 4 heads ====
  #pragma unroll 1
  for (int hh = 0; hh < 4; ++hh){
    const short* mtp = wsS + MTP_S + (4 + hh)*1024;
    // EA2: attn(Qe, K0, V0) -> blk 32 + hh*4 + e; e==0 also folds EA1 blk 16 + hh*4
    #pragma unroll 1
    for (int e = 0; e < 4; ++e){
      short8 xq = projXq(mtp, xw + e*2048, rho, l);
      f4v s0 = {0.f,0.f,0.f,0.f}, s1 = {0.f,0.f,0.f,0.f};
      f4v s2 = {0.f,0.f,0.f,0.f}, s3 = {0.f,0.f,0.f,0.f};
      s0 = MFMA(ldsA(xw, 32,  0, 0, l), xq, s0);
      s1 = MFMA(ldsA(xw, 32, 16, 0, l), xq, s1);
      s2 = MFMA(ldsA(xw, 32, 32, 0, l), xq, s2);
      s3 = MFMA(ldsA(xw, 32, 48, 0, l), xq, s3);
      unitTail(s0, s1, s2, s3, xtp, wsS,
               32 + hh*4 + e, (e == 0) ? (16 + hh*4) : -1, beta, g1, g2, l);
    }
    // EA1: attn(Q0, Ke, Ve) e=1..3 -> blk 16 + hh*4 + e
    short8 xq0 = projXq(mtp, xw, rho, l);
    #pragma unroll 1
    for (int e = 1; e < 4; ++e){
      f4v s0 = {0.f,0.f,0.f,0.f}, s1 = {0.f,0.f,0.f,0.f};
      f4v s2 = {0.f,0.f,0.f,0.f}, s3 = {0.f,0.f,0.f,0.f};
      s0 = MFMA(ldsA(xw + e*2048, 32,  0, 0, l), xq0, s0);
      s1 = MFMA(ldsA(xw + e*2048, 32, 16, 0, l), xq0, s1);
      s2 = MFMA(ldsA(xw + e*2048, 32, 32, 0, l), xq0, s2);
      s3 = MFMA(ldsA(xw + e*2048, 32, 48, 0, l), xq0, s3);
      unitTail(s0, s1, s2, s3, xtp + e*2304, wsS,
               16 + hh*4 + e, -1, beta, g1, g2, l);
    }
  }

  // ==== epilogue: bias + gelu -> aw (global, this block's column half) ====
  {
    short* awb = aw + (size_t)win * 8192 + beta*64;
    #pragma unroll
    for (int ct = 0; ct < 4; ++ct){
      int ol = ct*16 + (l & 15);
      int og = beta*64 + ol;
      float b1 = fc11b_[og], b2 = fc12b_[og];
      #pragma unroll
      for (int r = 0; r < 4; ++r)
        awb[(row0 + r)*128 + ol] = f2b(geluf(g1[ct][r] + b1) * (g2[ct][r] + b2));
    }
  }
}

// -------------------------------------------------------------- kernel B --
// grid 512 = 2 b x 128 rows x 2 px-halves; 64 px per block. Applies fc2 to the
// gathered GEGLU activations, then residual + LN + MLP + residual.
struct __align__(16) SmemB {
  float x1t[128][66];    // 33792 : x1 accumulates x + y (native [ch][px])
  short apx[64][136];    // 17408 : gathered a [px][o]; later reused as ab
  short xnt[64][136];    // 17408 : LN'd, px-major [px][ch]
};                       // 68608 B -> 2 blocks/CU

__global__ __launch_bounds__(256, 2) void kernelB(
    const float* __restrict__ x,
    const float* __restrict__ fc2b_,
    const float* __restrict__ ln2g, const float* __restrict__ ln2b,
    const float* __restrict__ m11b, const float* __restrict__ m12b,
    const float* __restrict__ m2b,
    const short* __restrict__ wsS, const short* __restrict__ aw,
    float* __restrict__ out)
{
  __shared__ SmemB sm;
  const int t = threadIdx.x, l = t & 63, w = t >> 6;
  const int id = blockIdx.x;
  const int b = id >> 8, rr = (id >> 1) & 127, chi = id & 1;
  const short* fc2 = wsS + FC2_S;
  const short* m11 = wsS + M11_S;
  const short* m12 = wsS + M12_S;
  const short* m2  = wsS + M2_S;

  // 1) load x tile: x1t[ch][pl] = x[b][ch][rr][chi*64 + pl]
  {
    const float* xb = x + (size_t)b * 2097152 + (size_t)rr * 128 + chi*64;
    for (int fid = t; fid < 2048; fid += 256){
      int ch = fid >> 4, q4 = fid & 15;
      *(f4v*)&sm.x1t[ch][q4*4] = *(const f4v*)(xb + (size_t)ch * 16384 + q4*4);
    }
  }
  // 2) gather a: apx[pl][o] from aw[win][tok][o]
  {
    int pl = t >> 2, oq = t & 3;
    int pxg = chi*64 + pl;
    int winl = b*256 + (rr & 15)*16 + (pxg & 15);
    int tok  = (rr >> 4)*8 + (pxg >> 4);
    const short* as = aw + (size_t)winl * 8192 + tok*128 + oq*32;
    #pragma unroll
    for (int k8 = 0; k8 < 4; ++k8)
      *(short8*)&sm.apx[pl][oq*32 + k8*8] = *(const short8*)(as + k8*8);
  }
  __syncthreads();
  // 3) y = a @ fc2^T + bias; x1t += y   (wave w owns px rows w*16..+15)
  {
    f4v z[8];
    #pragma unroll
    for (int i = 0; i < 8; ++i) z[i] = (f4v){0.f,0.f,0.f,0.f};
    #pragma unroll
    for (int ks = 0; ks < 4; ++ks){
      short8 a = ldsA(&sm.apx[0][0], 136, w*16, ks*32, l);
      const short* pB = fc2 + (l & 15)*128 + ks*32 + ((l >> 4) << 3);
      #pragma unroll
      for (int ct = 0; ct < 8; ++ct)
        z[ct] = MFMA(a, *(const short8*)(pB + ct*16*128), z[ct]);
    }
    #pragma unroll
    for (int ct = 0; ct < 8; ++ct){
      int ch = ct*16 + (l & 15);
      float bz = fc2b_[ch];
      #pragma unroll
      for (int r = 0; r < 4; ++r){
        int px = w*16 + ((l >> 4) << 2) + r;
        sm.x1t[ch][px] += z[ct][r] + bz;
      }
    }
  }
  __syncthreads();
  // 4) LayerNorm over 128 ch per px -> xnt[px][ch]
  {
    int pl = t >> 2, qd = t & 3;
    float s = 0.f;
    for (int i = 0; i < 32; ++i) s += sm.x1t[qd*32 + i][pl];
    s += __shfl_xor(s, 1);
    s += __shfl_xor(s, 2);
    float mu = s * (1.f/128.f);
    float vv = 0.f;
    for (int i = 0; i < 32; ++i){ float d = sm.x1t[qd*32 + i][pl] - mu; vv += d*d; }
    vv += __shfl_xor(vv, 1);
    vv += __shfl_xor(vv, 2);
    float rstd = rsqrtf(vv * (1.f/128.f) + 1e-5f);
    for (int i4 = 0; i4 < 8; ++i4){
      s4v o;
      #pragma unroll
      for (int j = 0; j < 4; ++j){
        int ch = qd*32 + i4*4 + j;
        o[j] = f2b((sm.x1t[ch][pl] - mu) * rstd * ln2g[ch] + ln2b[ch]);
      }
      *(s4v*)&sm.xnt[pl][qd*32 + i4*4] = o;
    }
  }
  __syncthreads();
  // 5) GEGLU MLP: G1/G2 -> gelu -> ab (apx reuse) -> m2 -> x1t +=
  {
    f4v G1[8], G2[8];
    #pragma unroll
    for (int i = 0; i < 8; ++i){
      G1[i] = (f4v){0.f,0.f,0.f,0.f};
      G2[i] = (f4v){0.f,0.f,0.f,0.f};
    }
    #pragma unroll
    for (int ks = 0; ks < 4; ++ks){
      short8 a = ldsA(&sm.xnt[0][0], 136, w*16, ks*32, l);
      const short* p1 = m11 + (l & 15)*128 + ks*32 + ((l >> 4) << 3);
      #pragma unroll
      for (int ct = 0; ct < 8; ++ct)
        G1[ct] = MFMA(a, *(const short8*)(p1 + ct*16*128), G1[ct]);
      const short* p2 = m12 + (l & 15)*128 + ks*32 + ((l >> 4) << 3);
      #pragma unroll
      for (int ct = 0; ct < 8; ++ct)
        G2[ct] = MFMA(a, *(const short8*)(p2 + ct*16*128), G2[ct]);
    }
    int r0 = w*16 + ((l >> 4) << 2);
    #pragma unroll
    for (int ct = 0; ct < 8; ++ct){
      int o = ct*16 + (l & 15);
      float bb1 = m11b[o], bb2 = m12b[o];
      #pragma unroll
      for (int r = 0; r < 4; ++r)
        sm.apx[r0 + r][o] = f2b(geluf(G1[ct][r] + bb1) * (G2[ct][r] + bb2));
    }
  }
  __syncthreads();
  {
    f4v Z[8];
    #pragma unroll
    for (int i = 0; i < 8; ++i) Z[i] = (f4v){0.f,0.f,0.f,0.f};
    #pragma unroll
    for (int ks = 0; ks < 4; ++ks){
      short8 a = ldsA(&sm.apx[0][0], 136, w*16, ks*32, l);
      const short* pz = m2 + (l & 15)*128 + ks*32 + ((l >> 4) << 3);
      #pragma unroll
      for (int ct = 0; ct < 8; ++ct)
        Z[ct] = MFMA(a, *(const short8*)(pz + ct*16*128), Z[ct]);
    }
    #pragma unroll
    for (int ct = 0; ct < 8; ++ct){
      int ch = ct*16 + (l & 15);
      float bz = m2b[ch];
      #pragma unroll
      for (int r = 0; r < 4; ++r){
        int px = w*16 + ((l >> 4) << 2) + r;
        sm.x1t[ch][px] += Z[ct][r] + bz;
      }
    }
  }
  __syncthreads();
  // 6) coalesced store
  {
    int ch = t >> 1, qh = t & 1;
    float* ob = out + ((size_t)b*128 + ch) * 16384 + (size_t)rr * 128 + chi*64 + qh*32;
    #pragma unroll
    for (int q4 = 0; q4 < 8; ++q4)
      *(f4v*)(ob + q4*4) = *(const f4v*)&sm.x1t[ch][qh*32 + q4*4];
  }
}

extern "C" void kernel_launch(void* const* d_in, const int* in_sizes, int n_in,
                              void* d_out, int out_size, void* d_ws, size_t ws_size,
                              hipStream_t stream) {
  (void)in_sizes; (void)n_in; (void)out_size; (void)ws_size;
  const float* x     = (const float*)d_in[0];
  const float* ln1g  = (const float*)d_in[1];
  const float* ln1b  = (const float*)d_in[2];
  const float* wea   = (const float*)d_in[3];
  const float* wsa   = (const float*)d_in[4];
  const float* rpb   = (const float*)d_in[5];
  const float* fc11w = (const float*)d_in[6];
  const float* fc11b = (const float*)d_in[7];
  const float* fc12w = (const float*)d_in[8];
  const float* fc12b = (const float*)d_in[9];
  const float* fc2w  = (const float*)d_in[10];
  const float* fc2b  = (const float*)d_in[11];
  const float* ln2g  = (const float*)d_in[12];
  const float* ln2b  = (const float*)d_in[13];
  const float* m11w  = (const float*)d_in[14];
  const float* m11b  = (const float*)d_in[15];
  const float* m12w  = (const float*)d_in[16];
  const float* m12b  = (const float*)d_in[17];
  const float* m2w   = (const float*)d_in[18];
  const float* m2b   = (const float*)d_in[19];

  short* wsS   = (short*)d_ws;
  float* biasP = (float*)((char*)d_ws + BIASP_B);
  short* aw    = (short*)((char*)d_ws + AW_B);

  prep<<<1024, 256, 0, stream>>>(wea, wsa, fc11w, fc12w, fc2w, m11w, m12w, m2w,
                                 rpb, wsS, biasP);
  kernelA<<<1024, 256, 0, stream>>>(x, ln1g, ln1b, fc11b, fc12b,
                                    wsS, biasP, aw);
  kernelB<<<512, 256, 0, stream>>>(x, fc2b, ln2g, ln2b, m11b, m12b, m2b,
                                   wsS, aw, (float*)d_out);
}

// Round 11
// 221.921 us; speedup vs baseline: 1.0006x; 1.0006x over previous
//
#include <hip/hip_runtime.h>
#include <hip/hip_bf16.h>
#include <cstdint>

#define SCALE 0.17677669529663687f  // 32^-0.5

typedef float f4v __attribute__((ext_vector_type(4)));
typedef short s4v __attribute__((ext_vector_type(4)));
typedef short short8 __attribute__((ext_vector_type(8)));

__device__ __forceinline__ float b2f(short s){
  return __uint_as_float(((unsigned)(unsigned short)s) << 16);
}
__device__ __forceinline__ short f2b(float f){
  unsigned u = __float_as_uint(f);
  unsigned r = (u + 0x7fffu + ((u >> 16) & 1u)) >> 16;
  return (short)r;
}
__device__ __forceinline__ float geluf(float x){
  return 0.5f * x * (1.0f + erff(x * 0.7071067811865476f));
}
__device__ __forceinline__ f4v MFMA(short8 a, short8 b, f4v c){
  return __builtin_amdgcn_mfma_f32_16x16x32_bf16(a, b, c, 0, 0, 0);
}
// A/B-pattern fragment from row-major [*][ld]: row = rowBase+(l&15), k = kBase+8*(l>>4)
__device__ __forceinline__ short8 ldsA(const short* base, int ld, int rowBase, int kBase, int l){
  return *(const short8*)(base + (rowBase + (l & 15)) * ld + kBase + ((l >> 4) << 3));
}
// pack two C-layout f4v tiles into a bf16 operand fragment: slot k' = 4*tile + r
__device__ __forceinline__ short8 pack8(f4v a0, f4v a1, float scl){
  short8 o;
  #pragma unroll
  for (int k = 0; k < 4; ++k){
    o[k]     = f2b(a0[k] * scl);
    o[k + 4] = f2b(a1[k] * scl);
  }
  return o;
}
// token permutation for XTP storage: slot(n) matches P-pack positional pairing
__device__ __forceinline__ int permTok(int n){
  return (n & 32) | (((n >> 2) & 3) << 3) | (((n >> 4) & 1) << 2) | (n & 3);
}

// ws short-offsets
#define MTP_S   0         // 8 blks * 1024  (SA h0..3, EA h0..3; row-permuted M^T, SCALE folded)
#define FWP1_S  8192      // 48 blks * 4096 (fc11-blk * Wv, col-slot-permuted)
#define FWP2_S  204800    // 48 blks * 4096 (fc12)
#define FC2_S   401408    // 16384
#define M11_S   417792
#define M12_S   434176
#define M2_S    450560
#define POS_S   466944    // 2048
#define BIASP_B 937984    // bytes: 16384 f32, slot-permuted rel-pos bias
#define AW_B    1048576   // bytes: bf16 GEGLU-activation region [win][tok][128]

// ---------------------------------------------------------------- prep ----
__global__ void prep(const float* __restrict__ wea, const float* __restrict__ wsa,
                     const float* __restrict__ fc11, const float* __restrict__ fc12,
                     const float* __restrict__ fc2,  const float* __restrict__ m11,
                     const float* __restrict__ m12,  const float* __restrict__ m2,
                     const float* __restrict__ rpb,
                     short* __restrict__ wsS, float* __restrict__ biasP)
{
  int gid = blockIdx.x * 256 + threadIdx.x;
  int stride = gridDim.x * 256;
  // FWP1 / FWP2: blk = br*16 + h*4 + e (br: 0=SA, 1=EA1, 2=EA2); [o][s], s=8*h4+k',
  // c(s) = 16*(k'>>2) + 4*h4 + (k'&3);  FW[o][c] = sum_f fc[o][cb+f] * Wv_h[f][c]
  for (int id = gid; id < 786432; id += stride){
    int isB = (id >= 393216);
    int i2 = isB ? id - 393216 : id;
    const float* fc = isB ? fc12 : fc11;
    int blk = i2 >> 12, rem = i2 & 4095;
    int o = rem >> 5, s = rem & 31;
    int h4 = (s >> 3) & 3, kp = s & 7;
    int c = 16*(kp >> 2) + 4*h4 + (kp & 3);
    int br = blk >> 4, h = (blk >> 2) & 3, e = blk & 3;
    int cb = h*128 + e*32 + (br == 0 ? 0 : (br == 1 ? 512 : 1024));
    const float* w = (br == 0) ? wsa : wea;
    float acc = 0.f;
    for (int f = 0; f < 32; ++f)
      acc += fc[o*1536 + cb + f] * w[(256 + h*32 + f)*32 + c];
    wsS[(isB ? FWP2_S : FWP1_S) + blk*4096 + o*32 + s] = f2b(acc);
  }
  // MTP: u = br*4 + h (br 0=SA wsa, 1=EA wea); row jp holds M^T row b = 8*h4+4*t+r
  for (int id = gid; id < 8192; id += stride){
    int u = id >> 10, jp = (id >> 5) & 31, a = id & 31;
    int h = u & 3;
    const float* w = (u < 4) ? wsa : wea;
    int t = jp >> 4, h4 = (jp >> 2) & 3, r = jp & 3;
    int b = 8*h4 + 4*t + r;
    float acc = 0.f;
    for (int d = 0; d < 32; ++d)
      acc += w[(h*32 + d)*32 + a] * w[(128 + h*32 + d)*32 + b];
    wsS[MTP_S + u*1024 + jp*32 + a] = f2b(acc * SCALE);
  }
  // plain bf16 copies
  for (int id = gid; id < 65536; id += stride){
    const float* src; int base; int off = id & 16383;
    switch (id >> 14){
      case 0:  src = fc2; base = FC2_S; break;
      case 1:  src = m11; base = M11_S; break;
      case 2:  src = m12; base = M12_S; break;
      default: src = m2;  base = M2_S;  break;
    }
    wsS[base + off] = f2b(src[off]);
  }
  // biasP[hh][i][h4][tj*4+r] = bias[i][j = tj*16 + 4*h4 + r]
  for (int id = gid; id < 16384; id += stride){
    int hh = id >> 12, i = (id >> 6) & 63, h4 = (id >> 4) & 3, tj = (id >> 2) & 3, r = id & 3;
    int j = tj*16 + 4*h4 + r;
    int idx = ((i >> 3) - (j >> 3) + 7)*15 + ((i & 7) - (j & 7) + 7);
    biasP[id] = rpb[idx*4 + hh];
  }
  // sine positional table (bf16, [n][c])
  if (gid < 64){
    const float invT[8] = {1.f, 0.316227766f, 0.1f, 0.0316227766f,
                           0.01f, 0.00316227766f, 0.001f, 0.000316227766f};
    const float ANG = 6.28318530717958647692f / 8.000001f;
    float ay = (float)((gid >> 3) + 1) * ANG;
    float ax = (float)((gid & 7) + 1) * ANG;
    #pragma unroll
    for (int m = 0; m < 8; ++m){
      float s, cc;
      sincosf(ay * invT[m], &s, &cc);
      wsS[POS_S + gid*32 + 2*m]      = f2b(s);
      wsS[POS_S + gid*32 + 2*m + 1]  = f2b(cc);
      sincosf(ax * invT[m], &s, &cc);
      wsS[POS_S + gid*32 + 16 + 2*m] = f2b(s);
      wsS[POS_S + gid*32 + 17 + 2*m] = f2b(cc);
    }
  }
}

// -------------------------------------------------------------- kernel A --
// grid 1024 = 512 windows x 2 column-halves (beta). 256 thr = 4 waves; wave rho
// owns 16 query rows, all 4 heads, GEGLU cols [beta*64, beta*64+64).
// LDS: xw[4][64][32] + XTP[4][32][72] = 34816 B -> 4 blocks/CU (16 waves/CU)
// NOTE: NOTHING in the hot path is address-taken (all accumulators are named
// f4v values passed by reference) -> no scratch demotion under the reg cap.
struct __align__(16) SmemA {
  short xw[8192];
  short xtp[9216];
};

__device__ __forceinline__ float smax16(f4v &s0, f4v &s1, f4v &s2, f4v &s3){
  float m = s0[0];
  #pragma unroll
  for (int r = 0; r < 4; ++r){
    m = fmaxf(m, s0[r]); m = fmaxf(m, s1[r]);
    m = fmaxf(m, s2[r]); m = fmaxf(m, s3[r]);
  }
  m = fmaxf(m, __shfl_xor(m, 16));
  m = fmaxf(m, __shfl_xor(m, 32));
  float sum = 0.f;
  #pragma unroll
  for (int r = 0; r < 4; ++r){
    float e0 = __expf(s0[r] - m), e1 = __expf(s1[r] - m);
    float e2 = __expf(s2[r] - m), e3 = __expf(s3[r] - m);
    s0[r] = e0; s1[r] = e1; s2[r] = e2; s3[r] = e3;
    sum += e0 + e1 + e2 + e3;
  }
  sum += __shfl_xor(sum, 16);
  sum += __shfl_xor(sum, 32);
  return __builtin_amdgcn_rcpf(sum);   // sum >= 1 -> safe approx reciprocal
}

__device__ __forceinline__ short8 projXq(const short* mtp, const short* xwE,
                                         int rho, int l){
  short8 xa = *(const short8*)(xwE + (rho*16 + (l & 15))*32 + ((l >> 4) << 3));
  f4v q0 = {0.f,0.f,0.f,0.f}, q1 = {0.f,0.f,0.f,0.f};
  q0 = MFMA(*(const short8*)(mtp + (l & 15)*32 + ((l >> 4) << 3)), xa, q0);
  q1 = MFMA(*(const short8*)(mtp + (16 + (l & 15))*32 + ((l >> 4) << 3)), xa, q1);
  return pack8(q0, q1, 1.f);
}

// g (4 col-tiles = half width) += mfma(rp, FWP blk rows [beta*64 ..)); no arrays.
__device__ __forceinline__ void geglu8(short8 rp, const short* wsS, int blk, int beta,
                                       f4v &g10, f4v &g11, f4v &g12, f4v &g13,
                                       f4v &g20, f4v &g21, f4v &g22, f4v &g23, int l){
  const short* f1 = wsS + FWP1_S + blk*4096 + beta*2048 + (l & 15)*32 + ((l >> 4) << 3);
  g10 = MFMA(rp, *(const short8*)(f1 +    0), g10);
  g11 = MFMA(rp, *(const short8*)(f1 +  512), g11);
  g12 = MFMA(rp, *(const short8*)(f1 + 1024), g12);
  g13 = MFMA(rp, *(const short8*)(f1 + 1536), g13);
  const short* f2 = wsS + FWP2_S + blk*4096 + beta*2048 + (l & 15)*32 + ((l >> 4) << 3);
  g20 = MFMA(rp, *(const short8*)(f2 +    0), g20);
  g21 = MFMA(rp, *(const short8*)(f2 +  512), g21);
  g22 = MFMA(rp, *(const short8*)(f2 + 1024), g22);
  g23 = MFMA(rp, *(const short8*)(f2 + 1536), g23);
}

__device__ __forceinline__ void unitTail(f4v s0, f4v s1, f4v s2, f4v s3,
                                         const short* xtpE, const short* wsS,
                                         int blk, int blkFold, int beta,
                                         f4v &g10, f4v &g11, f4v &g12, f4v &g13,
                                         f4v &g20, f4v &g21, f4v &g22, f4v &g23, int l){
  float inv = smax16(s0, s1, s2, s3);
  short8 pk0 = pack8(s0, s1, 1.f);
  short8 pk1 = pack8(s2, s3, 1.f);
  f4v rt0 = {0.f,0.f,0.f,0.f}, rt1 = {0.f,0.f,0.f,0.f};
  const short* x0 = xtpE + (l & 15)*72 + ((l >> 4) << 3);
  const short* x1 = xtpE + (16 + (l & 15))*72 + ((l >> 4) << 3);
  rt0 = MFMA(*(const short8*)(x0), pk0, rt0);
  rt0 = MFMA(*(const short8*)(x0 + 32), pk1, rt0);
  rt1 = MFMA(*(const short8*)(x1), pk0, rt1);
  rt1 = MFMA(*(const short8*)(x1 + 32), pk1, rt1);
  short8 rp = pack8(rt0, rt1, inv);
  geglu8(rp, wsS, blk, beta, g10, g11, g12, g13, g20, g21, g22, g23, l);
  if (blkFold >= 0)
    geglu8(rp, wsS, blkFold, beta, g10, g11, g12, g13, g20, g21, g22, g23, l);
}

__global__ __launch_bounds__(256, 4) void kernelA(
    const float* __restrict__ x,
    const float* __restrict__ ln1g, const float* __restrict__ ln1b,
    const float* __restrict__ fc11b_, const float* __restrict__ fc12b_,
    const short* __restrict__ wsS, const float* __restrict__ biasP,
    short* __restrict__ aw)
{
  __shared__ SmemA sm;
  short* xw  = sm.xw;       // [e][n][c] = e*2048 + n*32 + c
  short* xtp = sm.xtp;      // [e][c][pos] = e*2304 + c*72 + pos

  const int t = threadIdx.x, l = t & 63, w = t >> 6;
  const int rho = w;
  // XCD-aware bijective swizzle (1024 % 8 == 0)
  const int bw = ((blockIdx.x & 7) << 7) | (blockIdx.x >> 3);
  const int win = bw >> 1, beta = bw & 1;
  const int b = win >> 8, hw = win & 255, hi = hw >> 4, wj = hw & 15;
  const int row0 = rho*16 + ((l >> 4) << 2);
  const short* posb = wsS + POS_S;

  // ---- phase 0: window load + LayerNorm, two-pass (no local arrays) ----
  {
    const int e = w, n = l;
    const int c = n >> 1, i0 = (n & 1) * 4;
    const float* src = x + ((size_t)((b*4 + e)*32 + c) * 128 + hi*8) * 128 + wj*8;
    float sum = 0.f, ssq = 0.f;
    #pragma unroll
    for (int ii = 0; ii < 4; ++ii){
      f4v a  = *(const f4v*)(src + (size_t)(i0 + ii)*128);
      f4v bb = *(const f4v*)(src + (size_t)(i0 + ii)*128 + 4);
      #pragma unroll
      for (int k = 0; k < 4; ++k){
        sum += a[k] + bb[k];
        ssq += a[k]*a[k] + bb[k]*bb[k];
      }
    }
    float mu = sum * (1.f/32.f);
    float rstd = rsqrtf(ssq * (1.f/32.f) - mu*mu + 1e-5f);
    int pn = permTok(n);
    #pragma unroll
    for (int ii = 0; ii < 4; ++ii){
      f4v a  = *(const f4v*)(src + (size_t)(i0 + ii)*128);
      f4v bb = *(const f4v*)(src + (size_t)(i0 + ii)*128 + 4);
      s4v o0, o1;
      #pragma unroll
      for (int k = 0; k < 4; ++k){
        int ch = ii*8 + k;
        o0[k] = f2b((a[k]  - mu)*rstd*ln1g[ch]     + ln1b[ch]);
        o1[k] = f2b((bb[k] - mu)*rstd*ln1g[ch + 4] + ln1b[ch + 4]);
      }
      *(s4v*)&xw[e*2048 + n*32 + ii*8]     = o0;
      *(s4v*)&xw[e*2048 + n*32 + ii*8 + 4] = o1;
      #pragma unroll
      for (int k = 0; k < 4; ++k){
        xtp[e*2304 + (ii*8 + k)*72 + pn]     = o0[k];
        xtp[e*2304 + (ii*8 + k + 4)*72 + pn] = o1[k];
      }
    }
  }
  __syncthreads();

  f4v g10 = {0.f,0.f,0.f,0.f}, g11 = {0.f,0.f,0.f,0.f};
  f4v g12 = {0.f,0.f,0.f,0.f}, g13 = {0.f,0.f,0.f,0.f};
  f4v g20 = {0.f,0.f,0.f,0.f}, g21 = {0.f,0.f,0.f,0.f};
  f4v g22 = {0.f,0.f,0.f,0.f}, g23 = {0.f,0.f,0.f,0.f};

  // ==== SA: all 4 heads; y cols [0,512) ====
  #pragma unroll 1
  for (int hh = 0; hh < 4; ++hh){
    const short* mtp = wsS + MTP_S + hh*1024;
    f4v s0 = {0.f,0.f,0.f,0.f}, s1 = {0.f,0.f,0.f,0.f};
    f4v s2 = {0.f,0.f,0.f,0.f}, s3 = {0.f,0.f,0.f,0.f};
    #pragma unroll
    for (int e = 0; e < 4; ++e){
      short8 xq = projXq(mtp, xw + e*2048, rho, l);
      s0 = MFMA(ldsA(xw + e*2048, 32,  0, 0, l), xq, s0);
      s1 = MFMA(ldsA(xw + e*2048, 32, 16, 0, l), xq, s1);
      s2 = MFMA(ldsA(xw + e*2048, 32, 32, 0, l), xq, s2);
      s3 = MFMA(ldsA(xw + e*2048, 32, 48, 0, l), xq, s3);
    }
    const float* bb = biasP + ((hh*64 + rho*16 + (l & 15))*4 + (l >> 4)) * 16;
    s0 += *(const f4v*)(bb);
    s1 += *(const f4v*)(bb + 4);
    s2 += *(const f4v*)(bb + 8);
    s3 += *(const f4v*)(bb + 12);
    float inv = smax16(s0, s1, s2, s3);
    short8 pk0 = pack8(s0, s1, 1.f);
    short8 pk1 = pack8(s2, s3, 1.f);
    #pragma unroll 1
    for (int dc = 0; dc < 4; ++dc){
      const short* xt = xtp + dc*2304;
      f4v rt0 = {0.f,0.f,0.f,0.f}, rt1 = {0.f,0.f,0.f,0.f};
      const short* x0 = xt + (l & 15)*72 + ((l >> 4) << 3);
      const short* x1 = xt + (16 + (l & 15))*72 + ((l >> 4) << 3);
      rt0 = MFMA(*(const short8*)(x0), pk0, rt0);
      rt0 = MFMA(*(const short8*)(x0 + 32), pk1, rt0);
      rt1 = MFMA(*(const short8*)(x1), pk0, rt1);
      rt1 = MFMA(*(const short8*)(x1 + 32), pk1, rt1);
      short8 rp = pack8(rt0, rt1, inv);
      geglu8(rp, wsS, hh*4 + dc, beta,
             g10, g11, g12, g13, g20, g21, g22, g23, l);
    }
  }

  // ---- xw/XTP -> +pos (in place)
  __syncthreads();
  {
    const int e = w, n = l;
    #pragma unroll
    for (int c4 = 0; c4 < 8; ++c4){
      s4v xa = *(const s4v*)&xw[e*2048 + n*32 + c4*4];
      s4v pa = *(const s4v*)(posb + n*32 + c4*4);
      s4v o;
      #pragma unroll
      for (int j = 0; j < 4; ++j) o[j] = f2b(b2f(xa[j]) + b2f(pa[j]));
      *(s4v*)&xw[e*2048 + n*32 + c4*4] = o;
    }
    int pn = permTok(n);
    #pragma unroll
    for (int c2 = 0; c2 < 32; ++c2){
      int idx = e*2304 + c2*72 + pn;
      xtp[idx] = f2b(b2f(xtp[idx]) + b2f(posb[n*32 + c2]));
    }
  }
  __syncthreads();

  // ==== EA: all 4 heads ====
  #pragma unroll 1
  for (int hh = 0; hh < 4; ++hh){
    const short* mtp = wsS + MTP_S + (4 + hh)*1024;
    // EA2: attn(Qe, K0, V0) -> blk 32 + hh*4 + e; e==0 also folds EA1 blk 16 + hh*4
    #pragma unroll 1
    for (int e = 0; e < 4; ++e){
      short8 xq = projXq(mtp, xw + e*2048, rho, l);
      f4v s0 = {0.f,0.f,0.f,0.f}, s1 = {0.f,0.f,0.f,0.f};
      f4v s2 = {0.f,0.f,0.f,0.f}, s3 = {0.f,0.f,0.f,0.f};
      s0 = MFMA(ldsA(xw, 32,  0, 0, l), xq, s0);
      s1 = MFMA(ldsA(xw, 32, 16, 0, l), xq, s1);
      s2 = MFMA(ldsA(xw, 32, 32, 0, l), xq, s2);
      s3 = MFMA(ldsA(xw, 32, 48, 0, l), xq, s3);
      unitTail(s0, s1, s2, s3, xtp, wsS,
               32 + hh*4 + e, (e == 0) ? (16 + hh*4) : -1, beta,
               g10, g11, g12, g13, g20, g21, g22, g23, l);
    }
    // EA1: attn(Q0, Ke, Ve) e=1..3 -> blk 16 + hh*4 + e
    short8 xq0 = projXq(mtp, xw, rho, l);
    #pragma unroll 1
    for (int e = 1; e < 4; ++e){
      f4v s0 = {0.f,0.f,0.f,0.f}, s1 = {0.f,0.f,0.f,0.f};
      f4v s2 = {0.f,0.f,0.f,0.f}, s3 = {0.f,0.f,0.f,0.f};
      s0 = MFMA(ldsA(xw + e*2048, 32,  0, 0, l), xq0, s0);
      s1 = MFMA(ldsA(xw + e*2048, 32, 16, 0, l), xq0, s1);
      s2 = MFMA(ldsA(xw + e*2048, 32, 32, 0, l), xq0, s2);
      s3 = MFMA(ldsA(xw + e*2048, 32, 48, 0, l), xq0, s3);
      unitTail(s0, s1, s2, s3, xtp + e*2304, wsS,
               16 + hh*4 + e, -1, beta,
               g10, g11, g12, g13, g20, g21, g22, g23, l);
    }
  }

  // ==== epilogue: bias + gelu -> aw (global, this block's column half) ====
  {
    short* awb = aw + (size_t)win * 8192 + beta*64;
    auto epi = [&](int ct, f4v G1, f4v G2){
      int ol = ct*16 + (l & 15);
      int og = beta*64 + ol;
      float b1 = fc11b_[og], b2 = fc12b_[og];
      #pragma unroll
      for (int r = 0; r < 4; ++r)
        awb[(row0 + r)*128 + ol] = f2b(geluf(G1[r] + b1) * (G2[r] + b2));
    };
    epi(0, g10, g20);
    epi(1, g11, g21);
    epi(2, g12, g22);
    epi(3, g13, g23);
  }
}

// -------------------------------------------------------------- kernel B --
// grid 512 = 2 b x 128 rows x 2 px-halves; 64 px per block. Applies fc2 to the
// gathered GEGLU activations, then residual + LN + MLP + residual.
struct __align__(16) SmemB {
  float x1t[128][66];    // 33792 : x1 accumulates x + y (native [ch][px])
  short apx[64][136];    // 17408 : gathered a [px][o]; later reused as ab
  short xnt[64][136];    // 17408 : LN'd, px-major [px][ch]
};                       // 68608 B -> 2 blocks/CU

__global__ __launch_bounds__(256, 2) void kernelB(
    const float* __restrict__ x,
    const float* __restrict__ fc2b_,
    const float* __restrict__ ln2g, const float* __restrict__ ln2b,
    const float* __restrict__ m11b, const float* __restrict__ m12b,
    const float* __restrict__ m2b,
    const short* __restrict__ wsS, const short* __restrict__ aw,
    float* __restrict__ out)
{
  __shared__ SmemB sm;
  const int t = threadIdx.x, l = t & 63, w = t >> 6;
  const int id = blockIdx.x;
  const int b = id >> 8, rr = (id >> 1) & 127, chi = id & 1;
  const short* fc2 = wsS + FC2_S;
  const short* m11 = wsS + M11_S;
  const short* m12 = wsS + M12_S;
  const short* m2  = wsS + M2_S;

  // 1) load x tile: x1t[ch][pl] = x[b][ch][rr][chi*64 + pl]
  {
    const float* xb = x + (size_t)b * 2097152 + (size_t)rr * 128 + chi*64;
    for (int fid = t; fid < 2048; fid += 256){
      int ch = fid >> 4, q4 = fid & 15;
      *(f4v*)&sm.x1t[ch][q4*4] = *(const f4v*)(xb + (size_t)ch * 16384 + q4*4);
    }
  }
  // 2) gather a: apx[pl][o] from aw[win][tok][o]
  {
    int pl = t >> 2, oq = t & 3;
    int pxg = chi*64 + pl;
    int winl = b*256 + (rr & 15)*16 + (pxg & 15);
    int tok  = (rr >> 4)*8 + (pxg >> 4);
    const short* as = aw + (size_t)winl * 8192 + tok*128 + oq*32;
    #pragma unroll
    for (int k8 = 0; k8 < 4; ++k8)
      *(short8*)&sm.apx[pl][oq*32 + k8*8] = *(const short8*)(as + k8*8);
  }
  __syncthreads();
  // 3) y = a @ fc2^T + bias; x1t += y   (wave w owns px rows w*16..+15)
  {
    f4v z[8];
    #pragma unroll
    for (int i = 0; i < 8; ++i) z[i] = (f4v){0.f,0.f,0.f,0.f};
    #pragma unroll
    for (int ks = 0; ks < 4; ++ks){
      short8 a = ldsA(&sm.apx[0][0], 136, w*16, ks*32, l);
      const short* pB = fc2 + (l & 15)*128 + ks*32 + ((l >> 4) << 3);
      #pragma unroll
      for (int ct = 0; ct < 8; ++ct)
        z[ct] = MFMA(a, *(const short8*)(pB + ct*16*128), z[ct]);
    }
    #pragma unroll
    for (int ct = 0; ct < 8; ++ct){
      int ch = ct*16 + (l & 15);
      float bz = fc2b_[ch];
      #pragma unroll
      for (int r = 0; r < 4; ++r){
        int px = w*16 + ((l >> 4) << 2) + r;
        sm.x1t[ch][px] += z[ct][r] + bz;
      }
    }
  }
  __syncthreads();
  // 4) LayerNorm over 128 ch per px -> xnt[px][ch]
  {
    int pl = t >> 2, qd = t & 3;
    float s = 0.f;
    for (int i = 0; i < 32; ++i) s += sm.x1t[qd*32 + i][pl];
    s += __shfl_xor(s, 1);
    s += __shfl_xor(s, 2);
    float mu = s * (1.f/128.f);
    float vv = 0.f;
    for (int i = 0; i < 32; ++i){ float d = sm.x1t[qd*32 + i][pl] - mu; vv += d*d; }
    vv += __shfl_xor(vv, 1);
    vv += __shfl_xor(vv, 2);
    float rstd = rsqrtf(vv * (1.f/128.f) + 1e-5f);
    for (int i4 = 0; i4 < 8; ++i4){
      s4v o;
      #pragma unroll
      for (int j = 0; j < 4; ++j){
        int ch = qd*32 + i4*4 + j;
        o[j] = f2b((sm.x1t[ch][pl] - mu) * rstd * ln2g[ch] + ln2b[ch]);
      }
      *(s4v*)&sm.xnt[pl][qd*32 + i4*4] = o;
    }
  }
  __syncthreads();
  // 5) GEGLU MLP: G1/G2 -> gelu -> ab (apx reuse) -> m2 -> x1t +=
  {
    f4v G1[8], G2[8];
    #pragma unroll
    for (int i = 0; i < 8; ++i){
      G1[i] = (f4v){0.f,0.f,0.f,0.f};
      G2[i] = (f4v){0.f,0.f,0.f,0.f};
    }
    #pragma unroll
    for (int ks = 0; ks < 4; ++ks){
      short8 a = ldsA(&sm.xnt[0][0], 136, w*16, ks*32, l);
      const short* p1 = m11 + (l & 15)*128 + ks*32 + ((l >> 4) << 3);
      #pragma unroll
      for (int ct = 0; ct < 8; ++ct)
        G1[ct] = MFMA(a, *(const short8*)(p1 + ct*16*128), G1[ct]);
      const short* p2 = m12 + (l & 15)*128 + ks*32 + ((l >> 4) << 3);
      #pragma unroll
      for (int ct = 0; ct < 8; ++ct)
        G2[ct] = MFMA(a, *(const short8*)(p2 + ct*16*128), G2[ct]);
    }
    int r0 = w*16 + ((l >> 4) << 2);
    #pragma unroll
    for (int ct = 0; ct < 8; ++ct){
      int o = ct*16 + (l & 15);
      float bb1 = m11b[o], bb2 = m12b[o];
      #pragma unroll
      for (int r = 0; r < 4; ++r)
        sm.apx[r0 + r][o] = f2b(geluf(G1[ct][r] + bb1) * (G2[ct][r] + bb2));
    }
  }
  __syncthreads();
  {
    f4v Z[8];
    #pragma unroll
    for (int i = 0; i < 8; ++i) Z[i] = (f4v){0.f,0.f,0.f,0.f};
    #pragma unroll
    for (int ks = 0; ks < 4; ++ks){
      short8 a = ldsA(&sm.apx[0][0], 136, w*16, ks*32, l);
      const short* pz = m2 + (l & 15)*128 + ks*32 + ((l >> 4) << 3);
      #pragma unroll
      for (int ct = 0; ct < 8; ++ct)
        Z[ct] = MFMA(a, *(const short8*)(pz + ct*16*128), Z[ct]);
    }
    #pragma unroll
    for (int ct = 0; ct < 8; ++ct){
      int ch = ct*16 + (l & 15);
      float bz = m2b[ch];
      #pragma unroll
      for (int r = 0; r < 4; ++r){
        int px = w*16 + ((l >> 4) << 2) + r;
        sm.x1t[ch][px] += Z[ct][r] + bz;
      }
    }
  }
  __syncthreads();
  // 6) coalesced store
  {
    int ch = t >> 1, qh = t & 1;
    float* ob = out + ((size_t)b*128 + ch) * 16384 + (size_t)rr * 128 + chi*64 + qh*32;
    #pragma unroll
    for (int q4 = 0; q4 < 8; ++q4)
      *(f4v*)(ob + q4*4) = *(const f4v*)&sm.x1t[ch][qh*32 + q4*4];
  }
}

extern "C" void kernel_launch(void* const* d_in, const int* in_sizes, int n_in,
                              void* d_out, int out_size, void* d_ws, size_t ws_size,
                              hipStream_t stream) {
  (void)in_sizes; (void)n_in; (void)out_size; (void)ws_size;
  const float* x     = (const float*)d_in[0];
  const float* ln1g  = (const float*)d_in[1];
  const float* ln1b  = (const float*)d_in[2];
  const float* wea   = (const float*)d_in[3];
  const float* wsa   = (const float*)d_in[4];
  const float* rpb   = (const float*)d_in[5];
  const float* fc11w = (const float*)d_in[6];
  const float* fc11b = (const float*)d_in[7];
  const float* fc12w = (const float*)d_in[8];
  const float* fc12b = (const float*)d_in[9];
  const float* fc2w  = (const float*)d_in[10];
  const float* fc2b  = (const float*)d_in[11];
  const float* ln2g  = (const float*)d_in[12];
  const float* ln2b  = (const float*)d_in[13];
  const float* m11w  = (const float*)d_in[14];
  const float* m11b  = (const float*)d_in[15];
  const float* m12w  = (const float*)d_in[16];
  const float* m12b  = (const float*)d_in[17];
  const float* m2w   = (const float*)d_in[18];
  const float* m2b   = (const float*)d_in[19];

  short* wsS   = (short*)d_ws;
  float* biasP = (float*)((char*)d_ws + BIASP_B);
  short* aw    = (short*)((char*)d_ws + AW_B);

  prep<<<1024, 256, 0, stream>>>(wea, wsa, fc11w, fc12w, fc2w, m11w, m12w, m2w,
                                 rpb, wsS, biasP);
  kernelA<<<1024, 256, 0, stream>>>(x, ln1g, ln1b, fc11b, fc12b,
                                    wsS, biasP, aw);
  kernelB<<<512, 256, 0, stream>>>(x, fc2b, ln2g, ln2b, m11b, m12b, m2b,
                                   wsS, aw, (float*)d_out);
}

// Round 12
// 207.802 us; speedup vs baseline: 1.0686x; 1.0679x over previous
//
#include <hip/hip_runtime.h>
#include <hip/hip_bf16.h>
#include <cstdint>

#define SCALE 0.17677669529663687f  // 32^-0.5

typedef float f4v __attribute__((ext_vector_type(4)));
typedef short s4v __attribute__((ext_vector_type(4)));
typedef short short8 __attribute__((ext_vector_type(8)));

__device__ __forceinline__ float b2f(short s){
  return __uint_as_float(((unsigned)(unsigned short)s) << 16);
}
__device__ __forceinline__ short f2b(float f){
  unsigned u = __float_as_uint(f);
  unsigned r = (u + 0x7fffu + ((u >> 16) & 1u)) >> 16;
  return (short)r;
}
__device__ __forceinline__ float geluf(float x){
  return 0.5f * x * (1.0f + erff(x * 0.7071067811865476f));
}
__device__ __forceinline__ f4v MFMA(short8 a, short8 b, f4v c){
  return __builtin_amdgcn_mfma_f32_16x16x32_bf16(a, b, c, 0, 0, 0);
}
// A/B-pattern fragment from row-major [*][ld]: row = rowBase+(l&15), k = kBase+8*(l>>4)
__device__ __forceinline__ short8 ldsA(const short* base, int ld, int rowBase, int kBase, int l){
  return *(const short8*)(base + (rowBase + (l & 15)) * ld + kBase + ((l >> 4) << 3));
}
// pack two C-layout f4v tiles into a bf16 operand fragment: slot k' = 4*tile + r
__device__ __forceinline__ short8 pack8(f4v a0, f4v a1, float scl){
  short8 o;
  #pragma unroll
  for (int k = 0; k < 4; ++k){
    o[k]     = f2b(a0[k] * scl);
    o[k + 4] = f2b(a1[k] * scl);
  }
  return o;
}
// token permutation for XTP storage: slot(n) matches P-pack positional pairing
__device__ __forceinline__ int permTok(int n){
  return (n & 32) | (((n >> 2) & 3) << 3) | (((n >> 4) & 1) << 2) | (n & 3);
}

// ws short-offsets
#define MTP_S   0         // 8 blks * 1024  (SA h0..3, EA h0..3; row-permuted M^T, SCALE folded)
#define FWP1_S  8192      // 48 blks * 4096 (fc11-blk * Wv, col-slot-permuted)
#define FWP2_S  204800    // 48 blks * 4096 (fc12)
#define FC2_S   401408    // 16384
#define M11_S   417792
#define M12_S   434176
#define M2_S    450560
#define POS_S   466944    // 2048
#define BIASP_B 937984    // bytes: 16384 f32, slot-permuted rel-pos bias
#define AW_B    1048576   // bytes: bf16 GEGLU-activation region [win][tok][128]

// ---------------------------------------------------------------- prep ----
__global__ void prep(const float* __restrict__ wea, const float* __restrict__ wsa,
                     const float* __restrict__ fc11, const float* __restrict__ fc12,
                     const float* __restrict__ fc2,  const float* __restrict__ m11,
                     const float* __restrict__ m12,  const float* __restrict__ m2,
                     const float* __restrict__ rpb,
                     short* __restrict__ wsS, float* __restrict__ biasP)
{
  int gid = blockIdx.x * 256 + threadIdx.x;
  int stride = gridDim.x * 256;
  // FWP1 / FWP2: blk = br*16 + h*4 + e (br: 0=SA, 1=EA1, 2=EA2); [o][s], s=8*h4+k',
  // c(s) = 16*(k'>>2) + 4*h4 + (k'&3);  FW[o][c] = sum_f fc[o][cb+f] * Wv_h[f][c]
  for (int id = gid; id < 786432; id += stride){
    int isB = (id >= 393216);
    int i2 = isB ? id - 393216 : id;
    const float* fc = isB ? fc12 : fc11;
    int blk = i2 >> 12, rem = i2 & 4095;
    int o = rem >> 5, s = rem & 31;
    int h4 = (s >> 3) & 3, kp = s & 7;
    int c = 16*(kp >> 2) + 4*h4 + (kp & 3);
    int br = blk >> 4, h = (blk >> 2) & 3, e = blk & 3;
    int cb = h*128 + e*32 + (br == 0 ? 0 : (br == 1 ? 512 : 1024));
    const float* w = (br == 0) ? wsa : wea;
    float acc = 0.f;
    for (int f = 0; f < 32; ++f)
      acc += fc[o*1536 + cb + f] * w[(256 + h*32 + f)*32 + c];
    wsS[(isB ? FWP2_S : FWP1_S) + blk*4096 + o*32 + s] = f2b(acc);
  }
  // MTP: u = br*4 + h (br 0=SA wsa, 1=EA wea); row jp holds M^T row b = 8*h4+4*t+r
  for (int id = gid; id < 8192; id += stride){
    int u = id >> 10, jp = (id >> 5) & 31, a = id & 31;
    int h = u & 3;
    const float* w = (u < 4) ? wsa : wea;
    int t = jp >> 4, h4 = (jp >> 2) & 3, r = jp & 3;
    int b = 8*h4 + 4*t + r;
    float acc = 0.f;
    for (int d = 0; d < 32; ++d)
      acc += w[(h*32 + d)*32 + a] * w[(128 + h*32 + d)*32 + b];
    wsS[MTP_S + u*1024 + jp*32 + a] = f2b(acc * SCALE);
  }
  // plain bf16 copies
  for (int id = gid; id < 65536; id += stride){
    const float* src; int base; int off = id & 16383;
    switch (id >> 14){
      case 0:  src = fc2; base = FC2_S; break;
      case 1:  src = m11; base = M11_S; break;
      case 2:  src = m12; base = M12_S; break;
      default: src = m2;  base = M2_S;  break;
    }
    wsS[base + off] = f2b(src[off]);
  }
  // biasP[hh][i][h4][tj*4+r] = bias[i][j = tj*16 + 4*h4 + r]
  for (int id = gid; id < 16384; id += stride){
    int hh = id >> 12, i = (id >> 6) & 63, h4 = (id >> 4) & 3, tj = (id >> 2) & 3, r = id & 3;
    int j = tj*16 + 4*h4 + r;
    int idx = ((i >> 3) - (j >> 3) + 7)*15 + ((i & 7) - (j & 7) + 7);
    biasP[id] = rpb[idx*4 + hh];
  }
  // sine positional table (bf16, [n][c])
  if (gid < 64){
    const float invT[8] = {1.f, 0.316227766f, 0.1f, 0.0316227766f,
                           0.01f, 0.00316227766f, 0.001f, 0.000316227766f};
    const float ANG = 6.28318530717958647692f / 8.000001f;
    float ay = (float)((gid >> 3) + 1) * ANG;
    float ax = (float)((gid & 7) + 1) * ANG;
    #pragma unroll
    for (int m = 0; m < 8; ++m){
      float s, cc;
      sincosf(ay * invT[m], &s, &cc);
      wsS[POS_S + gid*32 + 2*m]      = f2b(s);
      wsS[POS_S + gid*32 + 2*m + 1]  = f2b(cc);
      sincosf(ax * invT[m], &s, &cc);
      wsS[POS_S + gid*32 + 16 + 2*m] = f2b(s);
      wsS[POS_S + gid*32 + 17 + 2*m] = f2b(cc);
    }
  }
}

// -------------------------------------------------------------- kernel A --
// grid 1024 = 512 windows x 2 column-halves (beta). 256 thr = 4 waves; wave rho
// owns 16 query rows, all 4 heads, GEGLU cols [beta*64, beta*64+64).
// LDS: xw[4][64][32] + XTP[4][32][72] = 34816 B.
// __launch_bounds__(256,3): cap 170 regs -- evidence r4/r6/r7-11 shows the
// GEGLU accumulators spill to scratch at cap 128 (52 MB excess WRITE); cap 170
// with the halved (32-reg) accumulator set should be spill-free.
struct __align__(16) SmemA {
  short xw[8192];
  short xtp[9216];
};

__device__ __forceinline__ float smax16(f4v &s0, f4v &s1, f4v &s2, f4v &s3){
  float m = s0[0];
  #pragma unroll
  for (int r = 0; r < 4; ++r){
    m = fmaxf(m, s0[r]); m = fmaxf(m, s1[r]);
    m = fmaxf(m, s2[r]); m = fmaxf(m, s3[r]);
  }
  m = fmaxf(m, __shfl_xor(m, 16));
  m = fmaxf(m, __shfl_xor(m, 32));
  float sum = 0.f;
  #pragma unroll
  for (int r = 0; r < 4; ++r){
    float e0 = __expf(s0[r] - m), e1 = __expf(s1[r] - m);
    float e2 = __expf(s2[r] - m), e3 = __expf(s3[r] - m);
    s0[r] = e0; s1[r] = e1; s2[r] = e2; s3[r] = e3;
    sum += e0 + e1 + e2 + e3;
  }
  sum += __shfl_xor(sum, 16);
  sum += __shfl_xor(sum, 32);
  return __builtin_amdgcn_rcpf(sum);   // sum >= 1 -> safe approx reciprocal
}

__device__ __forceinline__ short8 projXq(const short* mtp, const short* xwE,
                                         int rho, int l){
  short8 xa = *(const short8*)(xwE + (rho*16 + (l & 15))*32 + ((l >> 4) << 3));
  f4v q0 = {0.f,0.f,0.f,0.f}, q1 = {0.f,0.f,0.f,0.f};
  q0 = MFMA(*(const short8*)(mtp + (l & 15)*32 + ((l >> 4) << 3)), xa, q0);
  q1 = MFMA(*(const short8*)(mtp + (16 + (l & 15))*32 + ((l >> 4) << 3)), xa, q1);
  return pack8(q0, q1, 1.f);
}

// g (4 col-tiles = half width) += mfma(rp, FWP blk rows [beta*64 ..)); no arrays.
__device__ __forceinline__ void geglu8(short8 rp, const short* wsS, int blk, int beta,
                                       f4v &g10, f4v &g11, f4v &g12, f4v &g13,
                                       f4v &g20, f4v &g21, f4v &g22, f4v &g23, int l){
  const short* f1 = wsS + FWP1_S + blk*4096 + beta*2048 + (l & 15)*32 + ((l >> 4) << 3);
  g10 = MFMA(rp, *(const short8*)(f1 +    0), g10);
  g11 = MFMA(rp, *(const short8*)(f1 +  512), g11);
  g12 = MFMA(rp, *(const short8*)(f1 + 1024), g12);
  g13 = MFMA(rp, *(const short8*)(f1 + 1536), g13);
  const short* f2 = wsS + FWP2_S + blk*4096 + beta*2048 + (l & 15)*32 + ((l >> 4) << 3);
  g20 = MFMA(rp, *(const short8*)(f2 +    0), g20);
  g21 = MFMA(rp, *(const short8*)(f2 +  512), g21);
  g22 = MFMA(rp, *(const short8*)(f2 + 1024), g22);
  g23 = MFMA(rp, *(const short8*)(f2 + 1536), g23);
}

__device__ __forceinline__ void unitTail(f4v s0, f4v s1, f4v s2, f4v s3,
                                         const short* xtpE, const short* wsS,
                                         int blk, int blkFold, int beta,
                                         f4v &g10, f4v &g11, f4v &g12, f4v &g13,
                                         f4v &g20, f4v &g21, f4v &g22, f4v &g23, int l){
  float inv = smax16(s0, s1, s2, s3);
  short8 pk0 = pack8(s0, s1, 1.f);
  short8 pk1 = pack8(s2, s3, 1.f);
  f4v rt0 = {0.f,0.f,0.f,0.f}, rt1 = {0.f,0.f,0.f,0.f};
  const short* x0 = xtpE + (l & 15)*72 + ((l >> 4) << 3);
  const short* x1 = xtpE + (16 + (l & 15))*72 + ((l >> 4) << 3);
  rt0 = MFMA(*(const short8*)(x0), pk0, rt0);
  rt0 = MFMA(*(const short8*)(x0 + 32), pk1, rt0);
  rt1 = MFMA(*(const short8*)(x1), pk0, rt1);
  rt1 = MFMA(*(const short8*)(x1 + 32), pk1, rt1);
  short8 rp = pack8(rt0, rt1, inv);
  geglu8(rp, wsS, blk, beta, g10, g11, g12, g13, g20, g21, g22, g23, l);
  if (blkFold >= 0)
    geglu8(rp, wsS, blkFold, beta, g10, g11, g12, g13, g20, g21, g22, g23, l);
}

__global__ __launch_bounds__(256, 3) void kernelA(
    const float* __restrict__ x,
    const float* __restrict__ ln1g, const float* __restrict__ ln1b,
    const float* __restrict__ fc11b_, const float* __restrict__ fc12b_,
    const short* __restrict__ wsS, const float* __restrict__ biasP,
    short* __restrict__ aw)
{
  __shared__ SmemA sm;
  short* xw  = sm.xw;       // [e][n][c] = e*2048 + n*32 + c
  short* xtp = sm.xtp;      // [e][c][pos] = e*2304 + c*72 + pos

  const int t = threadIdx.x, l = t & 63, w = t >> 6;
  const int rho = w;
  // XCD-aware bijective swizzle (1024 % 8 == 0)
  const int bw = ((blockIdx.x & 7) << 7) | (blockIdx.x >> 3);
  const int win = bw >> 1, beta = bw & 1;
  const int b = win >> 8, hw = win & 255, hi = hw >> 4, wj = hw & 15;
  const int row0 = rho*16 + ((l >> 4) << 2);
  const short* posb = wsS + POS_S;

  // ---- phase 0: window load + LayerNorm, two-pass (no local arrays) ----
  {
    const int e = w, n = l;
    const int c = n >> 1, i0 = (n & 1) * 4;
    const float* src = x + ((size_t)((b*4 + e)*32 + c) * 128 + hi*8) * 128 + wj*8;
    float sum = 0.f, ssq = 0.f;
    #pragma unroll
    for (int ii = 0; ii < 4; ++ii){
      f4v a  = *(const f4v*)(src + (size_t)(i0 + ii)*128);
      f4v bb = *(const f4v*)(src + (size_t)(i0 + ii)*128 + 4);
      #pragma unroll
      for (int k = 0; k < 4; ++k){
        sum += a[k] + bb[k];
        ssq += a[k]*a[k] + bb[k]*bb[k];
      }
    }
    float mu = sum * (1.f/32.f);
    float rstd = rsqrtf(ssq * (1.f/32.f) - mu*mu + 1e-5f);
    int pn = permTok(n);
    #pragma unroll
    for (int ii = 0; ii < 4; ++ii){
      f4v a  = *(const f4v*)(src + (size_t)(i0 + ii)*128);
      f4v bb = *(const f4v*)(src + (size_t)(i0 + ii)*128 + 4);
      s4v o0, o1;
      #pragma unroll
      for (int k = 0; k < 4; ++k){
        int ch = ii*8 + k;
        o0[k] = f2b((a[k]  - mu)*rstd*ln1g[ch]     + ln1b[ch]);
        o1[k] = f2b((bb[k] - mu)*rstd*ln1g[ch + 4] + ln1b[ch + 4]);
      }
      *(s4v*)&xw[e*2048 + n*32 + ii*8]     = o0;
      *(s4v*)&xw[e*2048 + n*32 + ii*8 + 4] = o1;
      #pragma unroll
      for (int k = 0; k < 4; ++k){
        xtp[e*2304 + (ii*8 + k)*72 + pn]     = o0[k];
        xtp[e*2304 + (ii*8 + k + 4)*72 + pn] = o1[k];
      }
    }
  }
  __syncthreads();

  f4v g10 = {0.f,0.f,0.f,0.f}, g11 = {0.f,0.f,0.f,0.f};
  f4v g12 = {0.f,0.f,0.f,0.f}, g13 = {0.f,0.f,0.f,0.f};
  f4v g20 = {0.f,0.f,0.f,0.f}, g21 = {0.f,0.f,0.f,0.f};
  f4v g22 = {0.f,0.f,0.f,0.f}, g23 = {0.f,0.f,0.f,0.f};

  // ==== SA: all 4 heads; y cols [0,512) ====
  #pragma unroll 1
  for (int hh = 0; hh < 4; ++hh){
    const short* mtp = wsS + MTP_S + hh*1024;
    f4v s0 = {0.f,0.f,0.f,0.f}, s1 = {0.f,0.f,0.f,0.f};
    f4v s2 = {0.f,0.f,0.f,0.f}, s3 = {0.f,0.f,0.f,0.f};
    #pragma unroll
    for (int e = 0; e < 4; ++e){
      short8 xq = projXq(mtp, xw + e*2048, rho, l);
      s0 = MFMA(ldsA(xw + e*2048, 32,  0, 0, l), xq, s0);
      s1 = MFMA(ldsA(xw + e*2048, 32, 16, 0, l), xq, s1);
      s2 = MFMA(ldsA(xw + e*2048, 32, 32, 0, l), xq, s2);
      s3 = MFMA(ldsA(xw + e*2048, 32, 48, 0, l), xq, s3);
    }
    const float* bb = biasP + ((hh*64 + rho*16 + (l & 15))*4 + (l >> 4)) * 16;
    s0 += *(const f4v*)(bb);
    s1 += *(const f4v*)(bb + 4);
    s2 += *(const f4v*)(bb + 8);
    s3 += *(const f4v*)(bb + 12);
    float inv = smax16(s0, s1, s2, s3);
    short8 pk0 = pack8(s0, s1, 1.f);
    short8 pk1 = pack8(s2, s3, 1.f);
    #pragma unroll 1
    for (int dc = 0; dc < 4; ++dc){
      const short* xt = xtp + dc*2304;
      f4v rt0 = {0.f,0.f,0.f,0.f}, rt1 = {0.f,0.f,0.f,0.f};
      const short* x0 = xt + (l & 15)*72 + ((l >> 4) << 3);
      const short* x1 = xt + (16 + (l & 15))*72 + ((l >> 4) << 3);
      rt0 = MFMA(*(const short8*)(x0), pk0, rt0);
      rt0 = MFMA(*(const short8*)(x0 + 32), pk1, rt0);
      rt1 = MFMA(*(const short8*)(x1), pk0, rt1);
      rt1 = MFMA(*(const short8*)(x1 + 32), pk1, rt1);
      short8 rp = pack8(rt0, rt1, inv);
      geglu8(rp, wsS, hh*4 + dc, beta,
             g10, g11, g12, g13, g20, g21, g22, g23, l);
    }
  }

  // ---- xw/XTP -> +pos (in place)
  __syncthreads();
  {
    const int e = w, n = l;
    #pragma unroll
    for (int c4 = 0; c4 < 8; ++c4){
      s4v xa = *(const s4v*)&xw[e*2048 + n*32 + c4*4];
      s4v pa = *(const s4v*)(posb + n*32 + c4*4);
      s4v o;
      #pragma unroll
      for (int j = 0; j < 4; ++j) o[j] = f2b(b2f(xa[j]) + b2f(pa[j]));
      *(s4v*)&xw[e*2048 + n*32 + c4*4] = o;
    }
    int pn = permTok(n);
    #pragma unroll
    for (int c2 = 0; c2 < 32; ++c2){
      int idx = e*2304 + c2*72 + pn;
      xtp[idx] = f2b(b2f(xtp[idx]) + b2f(posb[n*32 + c2]));
    }
  }
  __syncthreads();

  // ==== EA: all 4 heads ====
  #pragma unroll 1
  for (int hh = 0; hh < 4; ++hh){
    const short* mtp = wsS + MTP_S + (4 + hh)*1024;
    // EA2: attn(Qe, K0, V0) -> blk 32 + hh*4 + e; e==0 also folds EA1 blk 16 + hh*4
    #pragma unroll 1
    for (int e = 0; e < 4; ++e){
      short8 xq = projXq(mtp, xw + e*2048, rho, l);
      f4v s0 = {0.f,0.f,0.f,0.f}, s1 = {0.f,0.f,0.f,0.f};
      f4v s2 = {0.f,0.f,0.f,0.f}, s3 = {0.f,0.f,0.f,0.f};
      s0 = MFMA(ldsA(xw, 32,  0, 0, l), xq, s0);
      s1 = MFMA(ldsA(xw, 32, 16, 0, l), xq, s1);
      s2 = MFMA(ldsA(xw, 32, 32, 0, l), xq, s2);
      s3 = MFMA(ldsA(xw, 32, 48, 0, l), xq, s3);
      unitTail(s0, s1, s2, s3, xtp, wsS,
               32 + hh*4 + e, (e == 0) ? (16 + hh*4) : -1, beta,
               g10, g11, g12, g13, g20, g21, g22, g23, l);
    }
    // EA1: attn(Q0, Ke, Ve) e=1..3 -> blk 16 + hh*4 + e
    short8 xq0 = projXq(mtp, xw, rho, l);
    #pragma unroll 1
    for (int e = 1; e < 4; ++e){
      f4v s0 = {0.f,0.f,0.f,0.f}, s1 = {0.f,0.f,0.f,0.f};
      f4v s2 = {0.f,0.f,0.f,0.f}, s3 = {0.f,0.f,0.f,0.f};
      s0 = MFMA(ldsA(xw + e*2048, 32,  0, 0, l), xq0, s0);
      s1 = MFMA(ldsA(xw + e*2048, 32, 16, 0, l), xq0, s1);
      s2 = MFMA(ldsA(xw + e*2048, 32, 32, 0, l), xq0, s2);
      s3 = MFMA(ldsA(xw + e*2048, 32, 48, 0, l), xq0, s3);
      unitTail(s0, s1, s2, s3, xtp + e*2304, wsS,
               16 + hh*4 + e, -1, beta,
               g10, g11, g12, g13, g20, g21, g22, g23, l);
    }
  }

  // ==== epilogue: bias + gelu -> aw (global, this block's column half) ====
  {
    short* awb = aw + (size_t)win * 8192 + beta*64;
    auto epi = [&](int ct, f4v G1, f4v G2){
      int ol = ct*16 + (l & 15);
      int og = beta*64 + ol;
      float b1 = fc11b_[og], b2 = fc12b_[og];
      #pragma unroll
      for (int r = 0; r < 4; ++r)
        awb[(row0 + r)*128 + ol] = f2b(geluf(G1[r] + b1) * (G2[r] + b2));
    };
    epi(0, g10, g20);
    epi(1, g11, g21);
    epi(2, g12, g22);
    epi(3, g13, g23);
  }
}

// -------------------------------------------------------------- kernel B --
// grid 512 = 2 b x 128 rows x 2 px-halves; 64 px per block. Applies fc2 to the
// gathered GEGLU activations, then residual + LN + MLP + residual.
struct __align__(16) SmemB {
  float x1t[128][66];    // 33792 : x1 accumulates x + y (native [ch][px])
  short apx[64][136];    // 17408 : gathered a [px][o]; later reused as ab
  short xnt[64][136];    // 17408 : LN'd, px-major [px][ch]
};                       // 68608 B -> 2 blocks/CU

__global__ __launch_bounds__(256, 2) void kernelB(
    const float* __restrict__ x,
    const float* __restrict__ fc2b_,
    const float* __restrict__ ln2g, const float* __restrict__ ln2b,
    const float* __restrict__ m11b, const float* __restrict__ m12b,
    const float* __restrict__ m2b,
    const short* __restrict__ wsS, const short* __restrict__ aw,
    float* __restrict__ out)
{
  __shared__ SmemB sm;
  const int t = threadIdx.x, l = t & 63, w = t >> 6;
  const int id = blockIdx.x;
  const int b = id >> 8, rr = (id >> 1) & 127, chi = id & 1;
  const short* fc2 = wsS + FC2_S;
  const short* m11 = wsS + M11_S;
  const short* m12 = wsS + M12_S;
  const short* m2  = wsS + M2_S;

  // 1) load x tile: x1t[ch][pl] = x[b][ch][rr][chi*64 + pl]
  {
    const float* xb = x + (size_t)b * 2097152 + (size_t)rr * 128 + chi*64;
    for (int fid = t; fid < 2048; fid += 256){
      int ch = fid >> 4, q4 = fid & 15;
      *(f4v*)&sm.x1t[ch][q4*4] = *(const f4v*)(xb + (size_t)ch * 16384 + q4*4);
    }
  }
  // 2) gather a: apx[pl][o] from aw[win][tok][o]
  {
    int pl = t >> 2, oq = t & 3;
    int pxg = chi*64 + pl;
    int winl = b*256 + (rr & 15)*16 + (pxg & 15);
    int tok  = (rr >> 4)*8 + (pxg >> 4);
    const short* as = aw + (size_t)winl * 8192 + tok*128 + oq*32;
    #pragma unroll
    for (int k8 = 0; k8 < 4; ++k8)
      *(short8*)&sm.apx[pl][oq*32 + k8*8] = *(const short8*)(as + k8*8);
  }
  __syncthreads();
  // 3) y = a @ fc2^T + bias; x1t += y   (wave w owns px rows w*16..+15)
  {
    f4v z[8];
    #pragma unroll
    for (int i = 0; i < 8; ++i) z[i] = (f4v){0.f,0.f,0.f,0.f};
    #pragma unroll
    for (int ks = 0; ks < 4; ++ks){
      short8 a = ldsA(&sm.apx[0][0], 136, w*16, ks*32, l);
      const short* pB = fc2 + (l & 15)*128 + ks*32 + ((l >> 4) << 3);
      #pragma unroll
      for (int ct = 0; ct < 8; ++ct)
        z[ct] = MFMA(a, *(const short8*)(pB + ct*16*128), z[ct]);
    }
    #pragma unroll
    for (int ct = 0; ct < 8; ++ct){
      int ch = ct*16 + (l & 15);
      float bz = fc2b_[ch];
      #pragma unroll
      for (int r = 0; r < 4; ++r){
        int px = w*16 + ((l >> 4) << 2) + r;
        sm.x1t[ch][px] += z[ct][r] + bz;
      }
    }
  }
  __syncthreads();
  // 4) LayerNorm over 128 ch per px -> xnt[px][ch]
  {
    int pl = t >> 2, qd = t & 3;
    float s = 0.f;
    for (int i = 0; i < 32; ++i) s += sm.x1t[qd*32 + i][pl];
    s += __shfl_xor(s, 1);
    s += __shfl_xor(s, 2);
    float mu = s * (1.f/128.f);
    float vv = 0.f;
    for (int i = 0; i < 32; ++i){ float d = sm.x1t[qd*32 + i][pl] - mu; vv += d*d; }
    vv += __shfl_xor(vv, 1);
    vv += __shfl_xor(vv, 2);
    float rstd = rsqrtf(vv * (1.f/128.f) + 1e-5f);
    for (int i4 = 0; i4 < 8; ++i4){
      s4v o;
      #pragma unroll
      for (int j = 0; j < 4; ++j){
        int ch = qd*32 + i4*4 + j;
        o[j] = f2b((sm.x1t[ch][pl] - mu) * rstd * ln2g[ch] + ln2b[ch]);
      }
      *(s4v*)&sm.xnt[pl][qd*32 + i4*4] = o;
    }
  }
  __syncthreads();
  // 5) GEGLU MLP: G1/G2 -> gelu -> ab (apx reuse) -> m2 -> x1t +=
  {
    f4v G1[8], G2[8];
    #pragma unroll
    for (int i = 0; i < 8; ++i){
      G1[i] = (f4v){0.f,0.f,0.f,0.f};
      G2[i] = (f4v){0.f,0.f,0.f,0.f};
    }
    #pragma unroll
    for (int ks = 0; ks < 4; ++ks){
      short8 a = ldsA(&sm.xnt[0][0], 136, w*16, ks*32, l);
      const short* p1 = m11 + (l & 15)*128 + ks*32 + ((l >> 4) << 3);
      #pragma unroll
      for (int ct = 0; ct < 8; ++ct)
        G1[ct] = MFMA(a, *(const short8*)(p1 + ct*16*128), G1[ct]);
      const short* p2 = m12 + (l & 15)*128 + ks*32 + ((l >> 4) << 3);
      #pragma unroll
      for (int ct = 0; ct < 8; ++ct)
        G2[ct] = MFMA(a, *(const short8*)(p2 + ct*16*128), G2[ct]);
    }
    int r0 = w*16 + ((l >> 4) << 2);
    #pragma unroll
    for (int ct = 0; ct < 8; ++ct){
      int o = ct*16 + (l & 15);
      float bb1 = m11b[o], bb2 = m12b[o];
      #pragma unroll
      for (int r = 0; r < 4; ++r)
        sm.apx[r0 + r][o] = f2b(geluf(G1[ct][r] + bb1) * (G2[ct][r] + bb2));
    }
  }
  __syncthreads();
  {
    f4v Z[8];
    #pragma unroll
    for (int i = 0; i < 8; ++i) Z[i] = (f4v){0.f,0.f,0.f,0.f};
    #pragma unroll
    for (int ks = 0; ks < 4; ++ks){
      short8 a = ldsA(&sm.apx[0][0], 136, w*16, ks*32, l);
      const short* pz = m2 + (l & 15)*128 + ks*32 + ((l >> 4) << 3);
      #pragma unroll
      for (int ct = 0; ct < 8; ++ct)
        Z[ct] = MFMA(a, *(const short8*)(pz + ct*16*128), Z[ct]);
    }
    #pragma unroll
    for (int ct = 0; ct < 8; ++ct){
      int ch = ct*16 + (l & 15);
      float bz = m2b[ch];
      #pragma unroll
      for (int r = 0; r < 4; ++r){
        int px = w*16 + ((l >> 4) << 2) + r;
        sm.x1t[ch][px] += Z[ct][r] + bz;
      }
    }
  }
  __syncthreads();
  // 6) coalesced store
  {
    int ch = t >> 1, qh = t & 1;
    float* ob = out + ((size_t)b*128 + ch) * 16384 + (size_t)rr * 128 + chi*64 + qh*32;
    #pragma unroll
    for (int q4 = 0; q4 < 8; ++q4)
      *(f4v*)(ob + q4*4) = *(const f4v*)&sm.x1t[ch][qh*32 + q4*4];
  }
}

extern "C" void kernel_launch(void* const* d_in, const int* in_sizes, int n_in,
                              void* d_out, int out_size, void* d_ws, size_t ws_size,
                              hipStream_t stream) {
  (void)in_sizes; (void)n_in; (void)out_size; (void)ws_size;
  const float* x     = (const float*)d_in[0];
  const float* ln1g  = (const float*)d_in[1];
  const float* ln1b  = (const float*)d_in[2];
  const float* wea   = (const float*)d_in[3];
  const float* wsa   = (const float*)d_in[4];
  const float* rpb   = (const float*)d_in[5];
  const float* fc11w = (const float*)d_in[6];
  const float* fc11b = (const float*)d_in[7];
  const float* fc12w = (const float*)d_in[8];
  const float* fc12b = (const float*)d_in[9];
  const float* fc2w  = (const float*)d_in[10];
  const float* fc2b  = (const float*)d_in[11];
  const float* ln2g  = (const float*)d_in[12];
  const float* ln2b  = (const float*)d_in[13];
  const float* m11w  = (const float*)d_in[14];
  const float* m11b  = (const float*)d_in[15];
  const float* m12w  = (const float*)d_in[16];
  const float* m12b  = (const float*)d_in[17];
  const float* m2w   = (const float*)d_in[18];
  const float* m2b   = (const float*)d_in[19];

  short* wsS   = (short*)d_ws;
  float* biasP = (float*)((char*)d_ws + BIASP_B);
  short* aw    = (short*)((char*)d_ws + AW_B);

  prep<<<1024, 256, 0, stream>>>(wea, wsa, fc11w, fc12w, fc2w, m11w, m12w, m2w,
                                 rpb, wsS, biasP);
  kernelA<<<1024, 256, 0, stream>>>(x, ln1g, ln1b, fc11b, fc12b,
                                    wsS, biasP, aw);
  kernelB<<<512, 256, 0, stream>>>(x, fc2b, ln2g, ln2b, m11b, m12b, m2b,
                                   wsS, aw, (float*)d_out);
}

// Round 13
// 202.637 us; speedup vs baseline: 1.0958x; 1.0255x over previous
//
#include <hip/hip_runtime.h>
#include <hip/hip_bf16.h>
#include <cstdint>

#define SCALE 0.17677669529663687f  // 32^-0.5

typedef float f4v __attribute__((ext_vector_type(4)));
typedef short s4v __attribute__((ext_vector_type(4)));
typedef short short8 __attribute__((ext_vector_type(8)));

__device__ __forceinline__ float b2f(short s){
  return __uint_as_float(((unsigned)(unsigned short)s) << 16);
}
// RNE f32->bf16 via the HIP intrinsic: compiler pairs adjacent casts into
// v_cvt_pk_bf16_f32 (m240: scalar casts beat hand-written cvt_pk asm).
__device__ __forceinline__ short f2b(float f){
  __hip_bfloat16 h = __float2bfloat16(f);
  return *reinterpret_cast<short*>(&h);
}
__device__ __forceinline__ float geluf(float x){
  return 0.5f * x * (1.0f + erff(x * 0.7071067811865476f));
}
__device__ __forceinline__ f4v MFMA(short8 a, short8 b, f4v c){
  return __builtin_amdgcn_mfma_f32_16x16x32_bf16(a, b, c, 0, 0, 0);
}
// A/B-pattern fragment from row-major [*][ld]: row = rowBase+(l&15), k = kBase+8*(l>>4)
__device__ __forceinline__ short8 ldsA(const short* base, int ld, int rowBase, int kBase, int l){
  return *(const short8*)(base + (rowBase + (l & 15)) * ld + kBase + ((l >> 4) << 3));
}
// pack two C-layout f4v tiles into a bf16 operand fragment: slot k' = 4*tile + r
__device__ __forceinline__ short8 pack8(f4v a0, f4v a1, float scl){
  short8 o;
  #pragma unroll
  for (int k = 0; k < 4; ++k){
    o[k]     = f2b(a0[k] * scl);
    o[k + 4] = f2b(a1[k] * scl);
  }
  return o;
}
// token permutation for XTP storage: slot(n) matches P-pack positional pairing
__device__ __forceinline__ int permTok(int n){
  return (n & 32) | (((n >> 2) & 3) << 3) | (((n >> 4) & 1) << 2) | (n & 3);
}

// ws short-offsets
#define MTP_S   0         // 8 blks * 1024  (SA h0..3, EA h0..3; row-permuted M^T, SCALE folded)
#define FWP1_S  8192      // 48 blks * 4096 (fc11-blk * Wv, col-slot-permuted)
#define FWP2_S  204800    // 48 blks * 4096 (fc12)
#define FC2_S   401408    // 16384
#define M11_S   417792
#define M12_S   434176
#define M2_S    450560
#define POS_S   466944    // 2048
#define BIASP_B 937984    // bytes: 16384 f32, slot-permuted rel-pos bias
#define AW_B    1048576   // bytes: bf16 GEGLU-activation region [win][tok][128]

// ---------------------------------------------------------------- prep ----
__global__ void prep(const float* __restrict__ wea, const float* __restrict__ wsa,
                     const float* __restrict__ fc11, const float* __restrict__ fc12,
                     const float* __restrict__ fc2,  const float* __restrict__ m11,
                     const float* __restrict__ m12,  const float* __restrict__ m2,
                     const float* __restrict__ rpb,
                     short* __restrict__ wsS, float* __restrict__ biasP)
{
  int gid = blockIdx.x * 256 + threadIdx.x;
  int stride = gridDim.x * 256;
  // FWP1 / FWP2: blk = br*16 + h*4 + e (br: 0=SA, 1=EA1, 2=EA2); [o][s], s=8*h4+k',
  // c(s) = 16*(k'>>2) + 4*h4 + (k'&3);  FW[o][c] = sum_f fc[o][cb+f] * Wv_h[f][c]
  for (int id = gid; id < 786432; id += stride){
    int isB = (id >= 393216);
    int i2 = isB ? id - 393216 : id;
    const float* fc = isB ? fc12 : fc11;
    int blk = i2 >> 12, rem = i2 & 4095;
    int o = rem >> 5, s = rem & 31;
    int h4 = (s >> 3) & 3, kp = s & 7;
    int c = 16*(kp >> 2) + 4*h4 + (kp & 3);
    int br = blk >> 4, h = (blk >> 2) & 3, e = blk & 3;
    int cb = h*128 + e*32 + (br == 0 ? 0 : (br == 1 ? 512 : 1024));
    const float* w = (br == 0) ? wsa : wea;
    float acc = 0.f;
    for (int f = 0; f < 32; ++f)
      acc += fc[o*1536 + cb + f] * w[(256 + h*32 + f)*32 + c];
    wsS[(isB ? FWP2_S : FWP1_S) + blk*4096 + o*32 + s] = f2b(acc);
  }
  // MTP: u = br*4 + h (br 0=SA wsa, 1=EA wea); row jp holds M^T row b = 8*h4+4*t+r
  for (int id = gid; id < 8192; id += stride){
    int u = id >> 10, jp = (id >> 5) & 31, a = id & 31;
    int h = u & 3;
    const float* w = (u < 4) ? wsa : wea;
    int t = jp >> 4, h4 = (jp >> 2) & 3, r = jp & 3;
    int b = 8*h4 + 4*t + r;
    float acc = 0.f;
    for (int d = 0; d < 32; ++d)
      acc += w[(h*32 + d)*32 + a] * w[(128 + h*32 + d)*32 + b];
    wsS[MTP_S + u*1024 + jp*32 + a] = f2b(acc * SCALE);
  }
  // plain bf16 copies
  for (int id = gid; id < 65536; id += stride){
    const float* src; int base; int off = id & 16383;
    switch (id >> 14){
      case 0:  src = fc2; base = FC2_S; break;
      case 1:  src = m11; base = M11_S; break;
      case 2:  src = m12; base = M12_S; break;
      default: src = m2;  base = M2_S;  break;
    }
    wsS[base + off] = f2b(src[off]);
  }
  // biasP[hh][i][h4][tj*4+r] = bias[i][j = tj*16 + 4*h4 + r]
  for (int id = gid; id < 16384; id += stride){
    int hh = id >> 12, i = (id >> 6) & 63, h4 = (id >> 4) & 3, tj = (id >> 2) & 3, r = id & 3;
    int j = tj*16 + 4*h4 + r;
    int idx = ((i >> 3) - (j >> 3) + 7)*15 + ((i & 7) - (j & 7) + 7);
    biasP[id] = rpb[idx*4 + hh];
  }
  // sine positional table (bf16, [n][c])
  if (gid < 64){
    const float invT[8] = {1.f, 0.316227766f, 0.1f, 0.0316227766f,
                           0.01f, 0.00316227766f, 0.001f, 0.000316227766f};
    const float ANG = 6.28318530717958647692f / 8.000001f;
    float ay = (float)((gid >> 3) + 1) * ANG;
    float ax = (float)((gid & 7) + 1) * ANG;
    #pragma unroll
    for (int m = 0; m < 8; ++m){
      float s, cc;
      sincosf(ay * invT[m], &s, &cc);
      wsS[POS_S + gid*32 + 2*m]      = f2b(s);
      wsS[POS_S + gid*32 + 2*m + 1]  = f2b(cc);
      sincosf(ax * invT[m], &s, &cc);
      wsS[POS_S + gid*32 + 16 + 2*m] = f2b(s);
      wsS[POS_S + gid*32 + 17 + 2*m] = f2b(cc);
    }
  }
}

// -------------------------------------------------------------- kernel A --
// grid 1024 = 512 windows x 2 column-halves (beta). 256 thr = 4 waves; wave rho
// owns 16 query rows, all 4 heads, GEGLU cols [beta*64, beta*64+64).
// LDS: xw[4][64][32] + XTP[4][32][72] = 34816 B.
// __launch_bounds__(256,3): cap 170 regs (cap 128 spilled the GEGLU
// accumulators -- 52 MB excess WRITE at r7-11; this config is spill-clean).
struct __align__(16) SmemA {
  short xw[8192];
  short xtp[9216];
};

__device__ __forceinline__ float smax16(f4v &s0, f4v &s1, f4v &s2, f4v &s3){
  float m = s0[0];
  #pragma unroll
  for (int r = 0; r < 4; ++r){
    m = fmaxf(m, s0[r]); m = fmaxf(m, s1[r]);
    m = fmaxf(m, s2[r]); m = fmaxf(m, s3[r]);
  }
  m = fmaxf(m, __shfl_xor(m, 16));
  m = fmaxf(m, __shfl_xor(m, 32));
  float sum = 0.f;
  #pragma unroll
  for (int r = 0; r < 4; ++r){
    float e0 = __expf(s0[r] - m), e1 = __expf(s1[r] - m);
    float e2 = __expf(s2[r] - m), e3 = __expf(s3[r] - m);
    s0[r] = e0; s1[r] = e1; s2[r] = e2; s3[r] = e3;
    sum += e0 + e1 + e2 + e3;
  }
  sum += __shfl_xor(sum, 16);
  sum += __shfl_xor(sum, 32);
  return __builtin_amdgcn_rcpf(sum);   // sum >= 1 -> safe approx reciprocal
}

__device__ __forceinline__ short8 projXq(const short* mtp, const short* xwE,
                                         int rho, int l){
  short8 xa = *(const short8*)(xwE + (rho*16 + (l & 15))*32 + ((l >> 4) << 3));
  f4v q0 = {0.f,0.f,0.f,0.f}, q1 = {0.f,0.f,0.f,0.f};
  q0 = MFMA(*(const short8*)(mtp + (l & 15)*32 + ((l >> 4) << 3)), xa, q0);
  q1 = MFMA(*(const short8*)(mtp + (16 + (l & 15))*32 + ((l >> 4) << 3)), xa, q1);
  return pack8(q0, q1, 1.f);
}

// g (4 col-tiles = half width) += mfma(rp, FWP blk rows [beta*64 ..)); no arrays.
__device__ __forceinline__ void geglu8(short8 rp, const short* wsS, int blk, int beta,
                                       f4v &g10, f4v &g11, f4v &g12, f4v &g13,
                                       f4v &g20, f4v &g21, f4v &g22, f4v &g23, int l){
  const short* f1 = wsS + FWP1_S + blk*4096 + beta*2048 + (l & 15)*32 + ((l >> 4) << 3);
  g10 = MFMA(rp, *(const short8*)(f1 +    0), g10);
  g11 = MFMA(rp, *(const short8*)(f1 +  512), g11);
  g12 = MFMA(rp, *(const short8*)(f1 + 1024), g12);
  g13 = MFMA(rp, *(const short8*)(f1 + 1536), g13);
  const short* f2 = wsS + FWP2_S + blk*4096 + beta*2048 + (l & 15)*32 + ((l >> 4) << 3);
  g20 = MFMA(rp, *(const short8*)(f2 +    0), g20);
  g21 = MFMA(rp, *(const short8*)(f2 +  512), g21);
  g22 = MFMA(rp, *(const short8*)(f2 + 1024), g22);
  g23 = MFMA(rp, *(const short8*)(f2 + 1536), g23);
}

__device__ __forceinline__ void unitTail(f4v s0, f4v s1, f4v s2, f4v s3,
                                         const short* xtpE, const short* wsS,
                                         int blk, int blkFold, int beta,
                                         f4v &g10, f4v &g11, f4v &g12, f4v &g13,
                                         f4v &g20, f4v &g21, f4v &g22, f4v &g23, int l){
  float inv = smax16(s0, s1, s2, s3);
  short8 pk0 = pack8(s0, s1, 1.f);
  short8 pk1 = pack8(s2, s3, 1.f);
  f4v rt0 = {0.f,0.f,0.f,0.f}, rt1 = {0.f,0.f,0.f,0.f};
  const short* x0 = xtpE + (l & 15)*72 + ((l >> 4) << 3);
  const short* x1 = xtpE + (16 + (l & 15))*72 + ((l >> 4) << 3);
  rt0 = MFMA(*(const short8*)(x0), pk0, rt0);
  rt0 = MFMA(*(const short8*)(x0 + 32), pk1, rt0);
  rt1 = MFMA(*(const short8*)(x1), pk0, rt1);
  rt1 = MFMA(*(const short8*)(x1 + 32), pk1, rt1);
  short8 rp = pack8(rt0, rt1, inv);
  geglu8(rp, wsS, blk, beta, g10, g11, g12, g13, g20, g21, g22, g23, l);
  if (blkFold >= 0)
    geglu8(rp, wsS, blkFold, beta, g10, g11, g12, g13, g20, g21, g22, g23, l);
}

__global__ __launch_bounds__(256, 3) void kernelA(
    const float* __restrict__ x,
    const float* __restrict__ ln1g, const float* __restrict__ ln1b,
    const float* __restrict__ fc11b_, const float* __restrict__ fc12b_,
    const short* __restrict__ wsS, const float* __restrict__ biasP,
    short* __restrict__ aw)
{
  __shared__ SmemA sm;
  short* xw  = sm.xw;       // [e][n][c] = e*2048 + n*32 + c
  short* xtp = sm.xtp;      // [e][c][pos] = e*2304 + c*72 + pos

  const int t = threadIdx.x, l = t & 63, w = t >> 6;
  const int rho = w;
  // XCD-aware bijective swizzle (1024 % 8 == 0)
  const int bw = ((blockIdx.x & 7) << 7) | (blockIdx.x >> 3);
  const int win = bw >> 1, beta = bw & 1;
  const int b = win >> 8, hw = win & 255, hi = hw >> 4, wj = hw & 15;
  const int row0 = rho*16 + ((l >> 4) << 2);
  const short* posb = wsS + POS_S;

  // ---- phase 0: window load + LayerNorm, two-pass (no local arrays) ----
  {
    const int e = w, n = l;
    const int c = n >> 1, i0 = (n & 1) * 4;
    const float* src = x + ((size_t)((b*4 + e)*32 + c) * 128 + hi*8) * 128 + wj*8;
    float sum = 0.f, ssq = 0.f;
    #pragma unroll
    for (int ii = 0; ii < 4; ++ii){
      f4v a  = *(const f4v*)(src + (size_t)(i0 + ii)*128);
      f4v bb = *(const f4v*)(src + (size_t)(i0 + ii)*128 + 4);
      #pragma unroll
      for (int k = 0; k < 4; ++k){
        sum += a[k] + bb[k];
        ssq += a[k]*a[k] + bb[k]*bb[k];
      }
    }
    float mu = sum * (1.f/32.f);
    float rstd = rsqrtf(ssq * (1.f/32.f) - mu*mu + 1e-5f);
    int pn = permTok(n);
    #pragma unroll
    for (int ii = 0; ii < 4; ++ii){
      f4v a  = *(const f4v*)(src + (size_t)(i0 + ii)*128);
      f4v bb = *(const f4v*)(src + (size_t)(i0 + ii)*128 + 4);
      s4v o0, o1;
      #pragma unroll
      for (int k = 0; k < 4; ++k){
        int ch = ii*8 + k;
        o0[k] = f2b((a[k]  - mu)*rstd*ln1g[ch]     + ln1b[ch]);
        o1[k] = f2b((bb[k] - mu)*rstd*ln1g[ch + 4] + ln1b[ch + 4]);
      }
      *(s4v*)&xw[e*2048 + n*32 + ii*8]     = o0;
      *(s4v*)&xw[e*2048 + n*32 + ii*8 + 4] = o1;
      #pragma unroll
      for (int k = 0; k < 4; ++k){
        xtp[e*2304 + (ii*8 + k)*72 + pn]     = o0[k];
        xtp[e*2304 + (ii*8 + k + 4)*72 + pn] = o1[k];
      }
    }
  }
  __syncthreads();

  f4v g10 = {0.f,0.f,0.f,0.f}, g11 = {0.f,0.f,0.f,0.f};
  f4v g12 = {0.f,0.f,0.f,0.f}, g13 = {0.f,0.f,0.f,0.f};
  f4v g20 = {0.f,0.f,0.f,0.f}, g21 = {0.f,0.f,0.f,0.f};
  f4v g22 = {0.f,0.f,0.f,0.f}, g23 = {0.f,0.f,0.f,0.f};

  // ==== SA: all 4 heads; y cols [0,512) ====
  #pragma unroll 1
  for (int hh = 0; hh < 4; ++hh){
    const short* mtp = wsS + MTP_S + hh*1024;
    f4v s0 = {0.f,0.f,0.f,0.f}, s1 = {0.f,0.f,0.f,0.f};
    f4v s2 = {0.f,0.f,0.f,0.f}, s3 = {0.f,0.f,0.f,0.f};
    #pragma unroll
    for (int e = 0; e < 4; ++e){
      short8 xq = projXq(mtp, xw + e*2048, rho, l);
      s0 = MFMA(ldsA(xw + e*2048, 32,  0, 0, l), xq, s0);
      s1 = MFMA(ldsA(xw + e*2048, 32, 16, 0, l), xq, s1);
      s2 = MFMA(ldsA(xw + e*2048, 32, 32, 0, l), xq, s2);
      s3 = MFMA(ldsA(xw + e*2048, 32, 48, 0, l), xq, s3);
    }
    const float* bb = biasP + ((hh*64 + rho*16 + (l & 15))*4 + (l >> 4)) * 16;
    s0 += *(const f4v*)(bb);
    s1 += *(const f4v*)(bb + 4);
    s2 += *(const f4v*)(bb + 8);
    s3 += *(const f4v*)(bb + 12);
    float inv = smax16(s0, s1, s2, s3);
    short8 pk0 = pack8(s0, s1, 1.f);
    short8 pk1 = pack8(s2, s3, 1.f);
    #pragma unroll 1
    for (int dc = 0; dc < 4; ++dc){
      const short* xt = xtp + dc*2304;
      f4v rt0 = {0.f,0.f,0.f,0.f}, rt1 = {0.f,0.f,0.f,0.f};
      const short* x0 = xt + (l & 15)*72 + ((l >> 4) << 3);
      const short* x1 = xt + (16 + (l & 15))*72 + ((l >> 4) << 3);
      rt0 = MFMA(*(const short8*)(x0), pk0, rt0);
      rt0 = MFMA(*(const short8*)(x0 + 32), pk1, rt0);
      rt1 = MFMA(*(const short8*)(x1), pk0, rt1);
      rt1 = MFMA(*(const short8*)(x1 + 32), pk1, rt1);
      short8 rp = pack8(rt0, rt1, inv);
      geglu8(rp, wsS, hh*4 + dc, beta,
             g10, g11, g12, g13, g20, g21, g22, g23, l);
    }
  }

  // ---- xw/XTP -> +pos (in place)
  __syncthreads();
  {
    const int e = w, n = l;
    #pragma unroll
    for (int c4 = 0; c4 < 8; ++c4){
      s4v xa = *(const s4v*)&xw[e*2048 + n*32 + c4*4];
      s4v pa = *(const s4v*)(posb + n*32 + c4*4);
      s4v o;
      #pragma unroll
      for (int j = 0; j < 4; ++j) o[j] = f2b(b2f(xa[j]) + b2f(pa[j]));
      *(s4v*)&xw[e*2048 + n*32 + c4*4] = o;
    }
    int pn = permTok(n);
    #pragma unroll
    for (int c2 = 0; c2 < 32; ++c2){
      int idx = e*2304 + c2*72 + pn;
      xtp[idx] = f2b(b2f(xtp[idx]) + b2f(posb[n*32 + c2]));
    }
  }
  __syncthreads();

  // ==== EA: all 4 heads ====
  #pragma unroll 1
  for (int hh = 0; hh < 4; ++hh){
    const short* mtp = wsS + MTP_S + (4 + hh)*1024;
    // EA2: attn(Qe, K0, V0) -> blk 32 + hh*4 + e; e==0 also folds EA1 blk 16 + hh*4
    #pragma unroll 1
    for (int e = 0; e < 4; ++e){
      short8 xq = projXq(mtp, xw + e*2048, rho, l);
      f4v s0 = {0.f,0.f,0.f,0.f}, s1 = {0.f,0.f,0.f,0.f};
      f4v s2 = {0.f,0.f,0.f,0.f}, s3 = {0.f,0.f,0.f,0.f};
      s0 = MFMA(ldsA(xw, 32,  0, 0, l), xq, s0);
      s1 = MFMA(ldsA(xw, 32, 16, 0, l), xq, s1);
      s2 = MFMA(ldsA(xw, 32, 32, 0, l), xq, s2);
      s3 = MFMA(ldsA(xw, 32, 48, 0, l), xq, s3);
      unitTail(s0, s1, s2, s3, xtp, wsS,
               32 + hh*4 + e, (e == 0) ? (16 + hh*4) : -1, beta,
               g10, g11, g12, g13, g20, g21, g22, g23, l);
    }
    // EA1: attn(Q0, Ke, Ve) e=1..3 -> blk 16 + hh*4 + e
    short8 xq0 = projXq(mtp, xw, rho, l);
    #pragma unroll 1
    for (int e = 1; e < 4; ++e){
      f4v s0 = {0.f,0.f,0.f,0.f}, s1 = {0.f,0.f,0.f,0.f};
      f4v s2 = {0.f,0.f,0.f,0.f}, s3 = {0.f,0.f,0.f,0.f};
      s0 = MFMA(ldsA(xw + e*2048, 32,  0, 0, l), xq0, s0);
      s1 = MFMA(ldsA(xw + e*2048, 32, 16, 0, l), xq0, s1);
      s2 = MFMA(ldsA(xw + e*2048, 32, 32, 0, l), xq0, s2);
      s3 = MFMA(ldsA(xw + e*2048, 32, 48, 0, l), xq0, s3);
      unitTail(s0, s1, s2, s3, xtp + e*2304, wsS,
               16 + hh*4 + e, -1, beta,
               g10, g11, g12, g13, g20, g21, g22, g23, l);
    }
  }

  // ==== epilogue: bias + gelu -> aw (global, this block's column half) ====
  {
    short* awb = aw + (size_t)win * 8192 + beta*64;
    auto epi = [&](int ct, f4v G1, f4v G2){
      int ol = ct*16 + (l & 15);
      int og = beta*64 + ol;
      float b1 = fc11b_[og], b2 = fc12b_[og];
      #pragma unroll
      for (int r = 0; r < 4; ++r)
        awb[(row0 + r)*128 + ol] = f2b(geluf(G1[r] + b1) * (G2[r] + b2));
    };
    epi(0, g10, g20);
    epi(1, g11, g21);
    epi(2, g12, g22);
    epi(3, g13, g23);
  }
}

// -------------------------------------------------------------- kernel B --
// grid 512 = 2 b x 128 rows x 2 px-halves; 64 px per block. Applies fc2 to the
// gathered GEGLU activations, then residual + LN + MLP + residual.
struct __align__(16) SmemB {
  float x1t[128][66];    // 33792 : x1 accumulates x + y (native [ch][px])
  short apx[64][136];    // 17408 : gathered a [px][o]; later reused as ab
  short xnt[64][136];    // 17408 : LN'd, px-major [px][ch]
};                       // 68608 B -> 2 blocks/CU

__global__ __launch_bounds__(256, 2) void kernelB(
    const float* __restrict__ x,
    const float* __restrict__ fc2b_,
    const float* __restrict__ ln2g, const float* __restrict__ ln2b,
    const float* __restrict__ m11b, const float* __restrict__ m12b,
    const float* __restrict__ m2b,
    const short* __restrict__ wsS, const short* __restrict__ aw,
    float* __restrict__ out)
{
  __shared__ SmemB sm;
  const int t = threadIdx.x, l = t & 63, w = t >> 6;
  const int id = blockIdx.x;
  const int b = id >> 8, rr = (id >> 1) & 127, chi = id & 1;
  const short* fc2 = wsS + FC2_S;
  const short* m11 = wsS + M11_S;
  const short* m12 = wsS + M12_S;
  const short* m2  = wsS + M2_S;

  // 1) load x tile: x1t[ch][pl] = x[b][ch][rr][chi*64 + pl]
  {
    const float* xb = x + (size_t)b * 2097152 + (size_t)rr * 128 + chi*64;
    for (int fid = t; fid < 2048; fid += 256){
      int ch = fid >> 4, q4 = fid & 15;
      *(f4v*)&sm.x1t[ch][q4*4] = *(const f4v*)(xb + (size_t)ch * 16384 + q4*4);
    }
  }
  // 2) gather a: apx[pl][o] from aw[win][tok][o]
  {
    int pl = t >> 2, oq = t & 3;
    int pxg = chi*64 + pl;
    int winl = b*256 + (rr & 15)*16 + (pxg & 15);
    int tok  = (rr >> 4)*8 + (pxg >> 4);
    const short* as = aw + (size_t)winl * 8192 + tok*128 + oq*32;
    #pragma unroll
    for (int k8 = 0; k8 < 4; ++k8)
      *(short8*)&sm.apx[pl][oq*32 + k8*8] = *(const short8*)(as + k8*8);
  }
  __syncthreads();
  // 3) y = a @ fc2^T + bias; x1t += y   (wave w owns px rows w*16..+15)
  {
    f4v z[8];
    #pragma unroll
    for (int i = 0; i < 8; ++i) z[i] = (f4v){0.f,0.f,0.f,0.f};
    #pragma unroll
    for (int ks = 0; ks < 4; ++ks){
      short8 a = ldsA(&sm.apx[0][0], 136, w*16, ks*32, l);
      const short* pB = fc2 + (l & 15)*128 + ks*32 + ((l >> 4) << 3);
      #pragma unroll
      for (int ct = 0; ct < 8; ++ct)
        z[ct] = MFMA(a, *(const short8*)(pB + ct*16*128), z[ct]);
    }
    #pragma unroll
    for (int ct = 0; ct < 8; ++ct){
      int ch = ct*16 + (l & 15);
      float bz = fc2b_[ch];
      #pragma unroll
      for (int r = 0; r < 4; ++r){
        int px = w*16 + ((l >> 4) << 2) + r;
        sm.x1t[ch][px] += z[ct][r] + bz;
      }
    }
  }
  __syncthreads();
  // 4) LayerNorm over 128 ch per px -> xnt[px][ch]
  {
    int pl = t >> 2, qd = t & 3;
    float s = 0.f;
    for (int i = 0; i < 32; ++i) s += sm.x1t[qd*32 + i][pl];
    s += __shfl_xor(s, 1);
    s += __shfl_xor(s, 2);
    float mu = s * (1.f/128.f);
    float vv = 0.f;
    for (int i = 0; i < 32; ++i){ float d = sm.x1t[qd*32 + i][pl] - mu; vv += d*d; }
    vv += __shfl_xor(vv, 1);
    vv += __shfl_xor(vv, 2);
    float rstd = rsqrtf(vv * (1.f/128.f) + 1e-5f);
    for (int i4 = 0; i4 < 8; ++i4){
      s4v o;
      #pragma unroll
      for (int j = 0; j < 4; ++j){
        int ch = qd*32 + i4*4 + j;
        o[j] = f2b((sm.x1t[ch][pl] - mu) * rstd * ln2g[ch] + ln2b[ch]);
      }
      *(s4v*)&sm.xnt[pl][qd*32 + i4*4] = o;
    }
  }
  __syncthreads();
  // 5) GEGLU MLP: G1/G2 -> gelu -> ab (apx reuse) -> m2 -> x1t +=
  {
    f4v G1[8], G2[8];
    #pragma unroll
    for (int i = 0; i < 8; ++i){
      G1[i] = (f4v){0.f,0.f,0.f,0.f};
      G2[i] = (f4v){0.f,0.f,0.f,0.f};
    }
    #pragma unroll
    for (int ks = 0; ks < 4; ++ks){
      short8 a = ldsA(&sm.xnt[0][0], 136, w*16, ks*32, l);
      const short* p1 = m11 + (l & 15)*128 + ks*32 + ((l >> 4) << 3);
      #pragma unroll
      for (int ct = 0; ct < 8; ++ct)
        G1[ct] = MFMA(a, *(const short8*)(p1 + ct*16*128), G1[ct]);
      const short* p2 = m12 + (l & 15)*128 + ks*32 + ((l >> 4) << 3);
      #pragma unroll
      for (int ct = 0; ct < 8; ++ct)
        G2[ct] = MFMA(a, *(const short8*)(p2 + ct*16*128), G2[ct]);
    }
    int r0 = w*16 + ((l >> 4) << 2);
    #pragma unroll
    for (int ct = 0; ct < 8; ++ct){
      int o = ct*16 + (l & 15);
      float bb1 = m11b[o], bb2 = m12b[o];
      #pragma unroll
      for (int r = 0; r < 4; ++r)
        sm.apx[r0 + r][o] = f2b(geluf(G1[ct][r] + bb1) * (G2[ct][r] + bb2));
    }
  }
  __syncthreads();
  {
    f4v Z[8];
    #pragma unroll
    for (int i = 0; i < 8; ++i) Z[i] = (f4v){0.f,0.f,0.f,0.f};
    #pragma unroll
    for (int ks = 0; ks < 4; ++ks){
      short8 a = ldsA(&sm.apx[0][0], 136, w*16, ks*32, l);
      const short* pz = m2 + (l & 15)*128 + ks*32 + ((l >> 4) << 3);
      #pragma unroll
      for (int ct = 0; ct < 8; ++ct)
        Z[ct] = MFMA(a, *(const short8*)(pz + ct*16*128), Z[ct]);
    }
    #pragma unroll
    for (int ct = 0; ct < 8; ++ct){
      int ch = ct*16 + (l & 15);
      float bz = m2b[ch];
      #pragma unroll
      for (int r = 0; r < 4; ++r){
        int px = w*16 + ((l >> 4) << 2) + r;
        sm.x1t[ch][px] += Z[ct][r] + bz;
      }
    }
  }
  __syncthreads();
  // 6) coalesced store
  {
    int ch = t >> 1, qh = t & 1;
    float* ob = out + ((size_t)b*128 + ch) * 16384 + (size_t)rr * 128 + chi*64 + qh*32;
    #pragma unroll
    for (int q4 = 0; q4 < 8; ++q4)
      *(f4v*)(ob + q4*4) = *(const f4v*)&sm.x1t[ch][qh*32 + q4*4];
  }
}

extern "C" void kernel_launch(void* const* d_in, const int* in_sizes, int n_in,
                              void* d_out, int out_size, void* d_ws, size_t ws_size,
                              hipStream_t stream) {
  (void)in_sizes; (void)n_in; (void)out_size; (void)ws_size;
  const float* x     = (const float*)d_in[0];
  const float* ln1g  = (const float*)d_in[1];
  const float* ln1b  = (const float*)d_in[2];
  const float* wea   = (const float*)d_in[3];
  const float* wsa   = (const float*)d_in[4];
  const float* rpb   = (const float*)d_in[5];
  const float* fc11w = (const float*)d_in[6];
  const float* fc11b = (const float*)d_in[7];
  const float* fc12w = (const float*)d_in[8];
  const float* fc12b = (const float*)d_in[9];
  const float* fc2w  = (const float*)d_in[10];
  const float* fc2b  = (const float*)d_in[11];
  const float* ln2g  = (const float*)d_in[12];
  const float* ln2b  = (const float*)d_in[13];
  const float* m11w  = (const float*)d_in[14];
  const float* m11b  = (const float*)d_in[15];
  const float* m12w  = (const float*)d_in[16];
  const float* m12b  = (const float*)d_in[17];
  const float* m2w   = (const float*)d_in[18];
  const float* m2b   = (const float*)d_in[19];

  short* wsS   = (short*)d_ws;
  float* biasP = (float*)((char*)d_ws + BIASP_B);
  short* aw    = (short*)((char*)d_ws + AW_B);

  prep<<<1024, 256, 0, stream>>>(wea, wsa, fc11w, fc12w, fc2w, m11w, m12w, m2w,
                                 rpb, wsS, biasP);
  kernelA<<<1024, 256, 0, stream>>>(x, ln1g, ln1b, fc11b, fc12b,
                                    wsS, biasP, aw);
  kernelB<<<512, 256, 0, stream>>>(x, fc2b, ln2g, ln2b, m11b, m12b, m2b,
                                   wsS, aw, (float*)d_out);
}